// Round 1
// baseline (702.856 us; speedup 1.0000x reference)
//
#include <hip/hip_runtime.h>
#include <cstddef>

#define BB 32
#define NN 256
#define RR 5
#define NEGF (-9.0e15f)

__device__ __forceinline__ float lrelu(float x) { return x >= 0.f ? x : 0.2f * x; }

// ---------------- pack y_bonds (B,N,N,5) int32 -> 5-bit mask per (b,i,j) ----------------
__global__ __launch_bounds__(256) void k_pack_mask(const int* __restrict__ bonds,
                                                   unsigned char* __restrict__ maskp) {
    int t = blockIdx.x * 256 + threadIdx.x;          // exactly B*N*N = 2,097,152 threads
    const int* p = bonds + (size_t)t * 5;
    unsigned m = 0;
#pragma unroll
    for (int r = 0; r < 5; ++r) m |= (p[r] == 1) ? (1u << r) : 0u;
    maskp[t] = (unsigned char)m;
}

// ---------------- h = A(M x K) @ W(K x 640) + bias ; optional leaky on A ----------------
template <int K, bool LEAKY>
__global__ __launch_bounds__(256) void k_gemm_h(const float* __restrict__ A,
                                                const float* __restrict__ W,
                                                const float* __restrict__ bias,
                                                float* __restrict__ Hout) {
    __shared__ float As[K][68];   // As[k][m], pad 68 keeps float4 reads aligned + banks spread
    __shared__ float Ws[K][64];   // Ws[k][n]
    const int t = threadIdx.x;
    const int m0 = blockIdx.y * 64, n0 = blockIdx.x * 64;

    for (int idx = t; idx < 64 * (K / 4); idx += 256) {
        int m = idx / (K / 4), kk = (idx % (K / 4)) * 4;
        float4 v = *(const float4*)&A[(size_t)(m0 + m) * K + kk];
        if (LEAKY) { v.x = lrelu(v.x); v.y = lrelu(v.y); v.z = lrelu(v.z); v.w = lrelu(v.w); }
        As[kk][m] = v.x; As[kk + 1][m] = v.y; As[kk + 2][m] = v.z; As[kk + 3][m] = v.w;
    }
    for (int idx = t; idx < 64 * (K / 4); idx += 256) {
        int k = idx / 16, n4 = (idx % 16) * 4;
        *(float4*)&Ws[k][n4] = *(const float4*)&W[(size_t)k * 640 + n0 + n4];
    }
    __syncthreads();

    const int tx = t & 15, ty = t >> 4;
    float acc[4][4] = {};
    for (int k = 0; k < K; ++k) {
        float4 av = *(const float4*)&As[k][ty * 4];
        float4 wv = *(const float4*)&Ws[k][tx * 4];
        float a0 = av.x, a1 = av.y, a2 = av.z, a3 = av.w;
        float w0 = wv.x, w1 = wv.y, w2 = wv.z, w3 = wv.w;
        acc[0][0] += a0 * w0; acc[0][1] += a0 * w1; acc[0][2] += a0 * w2; acc[0][3] += a0 * w3;
        acc[1][0] += a1 * w0; acc[1][1] += a1 * w1; acc[1][2] += a1 * w2; acc[1][3] += a1 * w3;
        acc[2][0] += a2 * w0; acc[2][1] += a2 * w1; acc[2][2] += a2 * w2; acc[2][3] += a2 * w3;
        acc[3][0] += a3 * w0; acc[3][1] += a3 * w1; acc[3][2] += a3 * w2; acc[3][3] += a3 * w3;
    }
    float4 bv = *(const float4*)&bias[n0 + tx * 4];
#pragma unroll
    for (int e = 0; e < 4; ++e) {
        float4 o;
        o.x = acc[e][0] + bv.x; o.y = acc[e][1] + bv.y;
        o.z = acc[e][2] + bv.z; o.w = acc[e][3] + bv.w;
        *(float4*)&Hout[(size_t)(m0 + ty * 4 + e) * 640 + n0 + tx * 4] = o;
    }
}

// ---------------- src[b,n,r] = h . a[r,:C] ; dst[b,n,r] = h . a[r,C:] ----------------
__global__ __launch_bounds__(256) void k_srcdst(const float* __restrict__ h,
                                                const float* __restrict__ a,
                                                float* __restrict__ src,
                                                float* __restrict__ dst) {
    int wid = threadIdx.x >> 6, lane = threadIdx.x & 63;
    int row = blockIdx.x * 4 + wid;                  // b*N + n
    const float* hr = h + (size_t)row * 640;
#pragma unroll
    for (int r = 0; r < 5; ++r) {
        float h0 = hr[r * 128 + lane], h1 = hr[r * 128 + 64 + lane];
        float s1 = h0 * a[r * 256 + lane] + h1 * a[r * 256 + 64 + lane];
        float s2 = h0 * a[r * 256 + 128 + lane] + h1 * a[r * 256 + 192 + lane];
#pragma unroll
        for (int o = 32; o > 0; o >>= 1) { s1 += __shfl_down(s1, o); s2 += __shfl_down(s2, o); }
        if (lane == 0) { src[row * 5 + r] = s1; dst[row * 5 + r] = s2; }
    }
}

// ---------------- softmax stats per (b,i): m = max, zinv = 1/sum(exp(.-m)) ----------------
__global__ __launch_bounds__(256) void k_stats(const float* __restrict__ src,
                                               const float* __restrict__ dst,
                                               const unsigned char* __restrict__ maskp,
                                               float* __restrict__ m_arr,
                                               float* __restrict__ zinv) {
    int row = blockIdx.x;                            // b*N + i
    int t = threadIdx.x;                             // j
    int b = row >> 8;
    float sv[5];
    {
        const float* sp = src + (size_t)row * 5;
#pragma unroll
        for (int r = 0; r < 5; ++r) sv[r] = sp[r];
    }
    const float* dp = dst + ((size_t)(b << 8) + t) * 5;
    unsigned mk = maskp[((size_t)row << 8) + t];
    float v[5];
#pragma unroll
    for (int r = 0; r < 5; ++r) {
        float xx = lrelu(sv[r] + dp[r]);
        v[r] = ((mk >> r) & 1) ? xx : NEGF;
    }
    float lmax = v[0];
#pragma unroll
    for (int r = 1; r < 5; ++r) lmax = fmaxf(lmax, v[r]);

    __shared__ float red[4], red2[4];
#pragma unroll
    for (int o = 32; o > 0; o >>= 1) lmax = fmaxf(lmax, __shfl_down(lmax, o));
    if ((t & 63) == 0) red[t >> 6] = lmax;
    __syncthreads();
    float m = fmaxf(fmaxf(red[0], red[1]), fmaxf(red[2], red[3]));

    float lsum = 0.f;
#pragma unroll
    for (int r = 0; r < 5; ++r) lsum += __expf(v[r] - m);
#pragma unroll
    for (int o = 32; o > 0; o >>= 1) lsum += __shfl_down(lsum, o);
    if ((t & 63) == 0) red2[t >> 6] = lsum;
    __syncthreads();
    if (t == 0) {
        float Z = red2[0] + red2[1] + red2[2] + red2[3];
        m_arr[row] = m;
        zinv[row] = 1.0f / Z;
    }
}

// ---------------- out[b,i,c] = sum_{j,r} p[b,i,j,r] * h[b,j,r,c] ----------------
// grid (2 j-splits, 8 i-tiles of 32, 32 b); out accumulated via atomicAdd (pre-zeroed)
__global__ __launch_bounds__(256) void k_agg(const float* __restrict__ h,
                                             const float* __restrict__ src,
                                             const float* __restrict__ dst,
                                             const unsigned char* __restrict__ maskp,
                                             const float* __restrict__ m_arr,
                                             const float* __restrict__ zinv,
                                             float* __restrict__ out) {
    __shared__ float Hs[80][128];   // k-tile (16 j x 5 r) x 128 c
    __shared__ float Ps[32][84];    // 32 i x 80 k (pad 84)
    const int t = threadIdx.x;
    const int js = blockIdx.x, itile = blockIdx.y, b = blockIdx.z;
    const int i0 = itile * 32;
    const float* Hb = h + (size_t)b * (NN * 640);    // (N*5, 128) rows are j*5+r
    const int tx = t & 15, iy = t >> 4;
    float acc[2][8] = {};

    for (int jt = 0; jt < 8; ++jt) {
        const int j0 = js * 128 + jt * 16;
        for (int idx = t; idx < 80 * 32; idx += 256) {
            int k = idx >> 5, c4 = (idx & 31) << 2;
            *(float4*)&Hs[k][c4] = *(const float4*)&Hb[(size_t)(j0 * 5 + k) * 128 + c4];
        }
        for (int idx = t; idx < 32 * 80; idx += 256) {
            int ii = idx / 80, k = idx - ii * 80;
            int i = i0 + ii, j = j0 + k / 5, r = k - (k / 5) * 5;
            unsigned mk = maskp[((size_t)(b * NN + i) << 8) + j];
            float v;
            if ((mk >> r) & 1) v = lrelu(src[(b * NN + i) * 5 + r] + dst[(b * NN + j) * 5 + r]);
            else               v = NEGF;
            Ps[ii][k] = __expf(v - m_arr[b * NN + i]) * zinv[b * NN + i];
        }
        __syncthreads();
        for (int k = 0; k < 80; ++k) {
            float p0 = Ps[2 * iy][k], p1 = Ps[2 * iy + 1][k];
            float4 ha = *(const float4*)&Hs[k][tx * 8];
            float4 hb = *(const float4*)&Hs[k][tx * 8 + 4];
            float hv[8] = {ha.x, ha.y, ha.z, ha.w, hb.x, hb.y, hb.z, hb.w};
#pragma unroll
            for (int c = 0; c < 8; ++c) { acc[0][c] += p0 * hv[c]; acc[1][c] += p1 * hv[c]; }
        }
        __syncthreads();
    }
#pragma unroll
    for (int e = 0; e < 2; ++e) {
        int gi = b * NN + i0 + 2 * iy + e;
#pragma unroll
        for (int c = 0; c < 8; ++c) atomicAdd(&out[(size_t)gi * 128 + tx * 8 + c], acc[e][c]);
    }
}

// ---------------- pooling: feats[b] = [mean_n h3, max_n h3] ----------------
__global__ __launch_bounds__(128) void k_pool(const float* __restrict__ h3,
                                              float* __restrict__ feats) {
    int b = blockIdx.x, c = threadIdx.x;
    float sm = 0.f, mx = -3.4e38f;
    for (int n = 0; n < NN; ++n) {
        float v = h3[((size_t)(b * NN + n)) * 128 + c];
        sm += v; mx = fmaxf(mx, v);
    }
    feats[b * 256 + c] = sm * (1.f / NN);
    feats[b * 256 + 128 + c] = mx;
}

// ---------------- MLP layer 1 (k-split partials): part[ks,b,o] ----------------
__global__ __launch_bounds__(256) void k_mlp1(const float* __restrict__ x,
                                              const float* __restrict__ feats,
                                              const float* __restrict__ We1,
                                              float* __restrict__ part) {
    int ks = blockIdx.x;                 // 0..3, k range [ks*320, ks*320+320)
    int b = blockIdx.y;
    int o = threadIdx.x;
    __shared__ float zs[320];
    for (int k = o; k < 320; k += 256) {
        int gk = ks * 320 + k;
        zs[k] = (gk < 1024) ? x[b * 1024 + gk] : feats[b * 256 + gk - 1024];
    }
    __syncthreads();
    float s = 0.f;
    for (int k = 0; k < 320; ++k) s += zs[k] * We1[(size_t)(ks * 320 + k) * 256 + o];
    part[(size_t)(ks * 32 + b) * 256 + o] = s;
}

// ---------------- MLP layers 2+3 ----------------
__global__ __launch_bounds__(256) void k_mlp23(const float* __restrict__ part,
                                               const float* __restrict__ be1,
                                               const float* __restrict__ We2,
                                               const float* __restrict__ be2,
                                               const float* __restrict__ We3,
                                               const float* __restrict__ be3,
                                               float* __restrict__ out) {
    int b = blockIdx.x, t = threadIdx.x;
    __shared__ float zs[256], z2s[32];
    float s = part[(size_t)(0 + b) * 256 + t] + part[(size_t)(32 + b) * 256 + t] +
              part[(size_t)(64 + b) * 256 + t] + part[(size_t)(96 + b) * 256 + t] + be1[t];
    zs[t] = lrelu(s);
    __syncthreads();
    if (t < 32) {
        float s2 = be2[t];
        for (int k = 0; k < 256; ++k) s2 += zs[k] * We2[k * 32 + t];
        z2s[t] = lrelu(s2);
    }
    __syncthreads();
    if (t == 0) {
        float s3 = be3[0];
#pragma unroll
        for (int k = 0; k < 32; ++k) s3 += z2s[k] * We3[k];
        out[b] = s3;
    }
}

// ---------------- workspace layout ----------------
constexpr size_t O_MASK = 0;                                   // 2,097,152 B
constexpr size_t O_H    = 2097152;                             // 8192*640*4
constexpr size_t O_SRC  = O_H + 8192ull * 640 * 4;
constexpr size_t O_DST  = O_SRC + 8192ull * 5 * 4;
constexpr size_t O_M    = O_DST + 8192ull * 5 * 4;
constexpr size_t O_Z    = O_M + 8192ull * 4;
constexpr size_t O_OUTA = O_Z + 8192ull * 4;
constexpr size_t O_OUTB = O_OUTA + 8192ull * 128 * 4;
constexpr size_t O_FEAT = O_OUTB + 8192ull * 128 * 4;
constexpr size_t O_PART = O_FEAT + 32ull * 256 * 4;            // ends ~31.9 MB

extern "C" void kernel_launch(void* const* d_in, const int* in_sizes, int n_in,
                              void* d_out, int out_size, void* d_ws, size_t ws_size,
                              hipStream_t stream) {
    const float* x       = (const float*)d_in[0];
    const float* y_atoms = (const float*)d_in[1];
    const int*   y_bonds = (const int*)d_in[2];
    const float* W1 = (const float*)d_in[3];
    const float* b1 = (const float*)d_in[4];
    const float* a1 = (const float*)d_in[5];
    const float* W2 = (const float*)d_in[6];
    const float* b2 = (const float*)d_in[7];
    const float* a2 = (const float*)d_in[8];
    const float* W3 = (const float*)d_in[9];
    const float* b3 = (const float*)d_in[10];
    const float* a3 = (const float*)d_in[11];
    const float* We1 = (const float*)d_in[12];
    const float* be1 = (const float*)d_in[13];
    const float* We2 = (const float*)d_in[14];
    const float* be2 = (const float*)d_in[15];
    const float* We3 = (const float*)d_in[16];
    const float* be3 = (const float*)d_in[17];
    float* out = (float*)d_out;

    char* ws = (char*)d_ws;
    unsigned char* maskp = (unsigned char*)(ws + O_MASK);
    float* h    = (float*)(ws + O_H);
    float* srcb = (float*)(ws + O_SRC);
    float* dstb = (float*)(ws + O_DST);
    float* marr = (float*)(ws + O_M);
    float* zinv = (float*)(ws + O_Z);
    float* outA = (float*)(ws + O_OUTA);
    float* outB = (float*)(ws + O_OUTB);
    float* feats = (float*)(ws + O_FEAT);
    float* part  = (float*)(ws + O_PART);

    dim3 blk(256);
    k_pack_mask<<<8192, blk, 0, stream>>>(y_bonds, maskp);

    // layer 1 (K=64, no leaky on input)
    k_gemm_h<64, false><<<dim3(10, 128), blk, 0, stream>>>(y_atoms, W1, b1, h);
    k_srcdst<<<2048, blk, 0, stream>>>(h, a1, srcb, dstb);
    k_stats<<<8192, blk, 0, stream>>>(srcb, dstb, maskp, marr, zinv);
    hipMemsetAsync(outA, 0, 8192ull * 128 * 4, stream);
    k_agg<<<dim3(2, 8, 32), blk, 0, stream>>>(h, srcb, dstb, maskp, marr, zinv, outA);

    // layer 2 (K=128, leaky on input)
    k_gemm_h<128, true><<<dim3(10, 128), blk, 0, stream>>>(outA, W2, b2, h);
    k_srcdst<<<2048, blk, 0, stream>>>(h, a2, srcb, dstb);
    k_stats<<<8192, blk, 0, stream>>>(srcb, dstb, maskp, marr, zinv);
    hipMemsetAsync(outB, 0, 8192ull * 128 * 4, stream);
    k_agg<<<dim3(2, 8, 32), blk, 0, stream>>>(h, srcb, dstb, maskp, marr, zinv, outB);

    // layer 3 (K=128, leaky on input)
    k_gemm_h<128, true><<<dim3(10, 128), blk, 0, stream>>>(outB, W3, b3, h);
    k_srcdst<<<2048, blk, 0, stream>>>(h, a3, srcb, dstb);
    k_stats<<<8192, blk, 0, stream>>>(srcb, dstb, maskp, marr, zinv);
    hipMemsetAsync(outA, 0, 8192ull * 128 * 4, stream);
    k_agg<<<dim3(2, 8, 32), blk, 0, stream>>>(h, srcb, dstb, maskp, marr, zinv, outA);

    // pooling + MLP
    k_pool<<<32, dim3(128), 0, stream>>>(outA, feats);
    k_mlp1<<<dim3(4, 32), blk, 0, stream>>>(x, feats, We1, part);
    k_mlp23<<<32, blk, 0, stream>>>(part, be1, We2, be2, We3, be3, out);
}

// Round 2
// 370.597 us; speedup vs baseline: 1.8966x; 1.8966x over previous
//
#include <hip/hip_runtime.h>
#include <cstddef>

#define BB 32
#define NN 256
#define RR 5
#define NEGF (-9.0e15f)

typedef __attribute__((ext_vector_type(8))) short bf16x8;
typedef __attribute__((ext_vector_type(4))) float f32x4;

__device__ __forceinline__ float lrelu(float x) { return x >= 0.f ? x : 0.2f * x; }
// RNE float -> bf16
__device__ __forceinline__ unsigned short f2bf(float x) {
    unsigned u = __float_as_uint(x);
    u += 0x7FFFu + ((u >> 16) & 1u);
    return (unsigned short)(u >> 16);
}

// ---------------- pack y_bonds (B,N,N,5) int32 -> 5-bit mask per (b,i,j) ----------------
__global__ __launch_bounds__(256) void k_pack_mask(const int* __restrict__ bonds,
                                                   unsigned char* __restrict__ maskp) {
    int t = blockIdx.x * 256 + threadIdx.x;          // exactly B*N*N = 2,097,152 threads
    const int* p = bonds + (size_t)t * 5;
    unsigned m = 0;
#pragma unroll
    for (int r = 0; r < 5; ++r) m |= (p[r] == 1) ? (1u << r) : 0u;
    maskp[t] = (unsigned char)m;
}

// ---------------- h = A(M x K) @ W(K x 640) + bias ; optional leaky on A ----------------
// Also emits hT: bf16, layout hT[b*128 + c][r*256 + j]  (row length 1280)
template <int K, bool LEAKY>
__global__ __launch_bounds__(256) void k_gemm_h(const float* __restrict__ A,
                                                const float* __restrict__ W,
                                                const float* __restrict__ bias,
                                                float* __restrict__ Hout,
                                                unsigned short* __restrict__ hT) {
    __shared__ float As[K][68];   // As[k][m]
    __shared__ float Ws[K][64];   // Ws[k][n]
    __shared__ unsigned short TT[64][66];  // transposed bf16 tile [n][m]
    const int t = threadIdx.x;
    const int m0 = blockIdx.y * 64, n0 = blockIdx.x * 64;

    for (int idx = t; idx < 64 * (K / 4); idx += 256) {
        int m = idx / (K / 4), kk = (idx % (K / 4)) * 4;
        float4 v = *(const float4*)&A[(size_t)(m0 + m) * K + kk];
        if (LEAKY) { v.x = lrelu(v.x); v.y = lrelu(v.y); v.z = lrelu(v.z); v.w = lrelu(v.w); }
        As[kk][m] = v.x; As[kk + 1][m] = v.y; As[kk + 2][m] = v.z; As[kk + 3][m] = v.w;
    }
    for (int idx = t; idx < 64 * (K / 4); idx += 256) {
        int k = idx / 16, n4 = (idx % 16) * 4;
        *(float4*)&Ws[k][n4] = *(const float4*)&W[(size_t)k * 640 + n0 + n4];
    }
    __syncthreads();

    const int tx = t & 15, ty = t >> 4;
    float acc[4][4] = {};
    for (int k = 0; k < K; ++k) {
        float4 av = *(const float4*)&As[k][ty * 4];
        float4 wv = *(const float4*)&Ws[k][tx * 4];
        float a0 = av.x, a1 = av.y, a2 = av.z, a3 = av.w;
        float w0 = wv.x, w1 = wv.y, w2 = wv.z, w3 = wv.w;
        acc[0][0] += a0 * w0; acc[0][1] += a0 * w1; acc[0][2] += a0 * w2; acc[0][3] += a0 * w3;
        acc[1][0] += a1 * w0; acc[1][1] += a1 * w1; acc[1][2] += a1 * w2; acc[1][3] += a1 * w3;
        acc[2][0] += a2 * w0; acc[2][1] += a2 * w1; acc[2][2] += a2 * w2; acc[2][3] += a2 * w3;
        acc[3][0] += a3 * w0; acc[3][1] += a3 * w1; acc[3][2] += a3 * w2; acc[3][3] += a3 * w3;
    }
    float4 bv = *(const float4*)&bias[n0 + tx * 4];
    float o[4][4];
#pragma unroll
    for (int e = 0; e < 4; ++e) {
        o[e][0] = acc[e][0] + bv.x; o[e][1] = acc[e][1] + bv.y;
        o[e][2] = acc[e][2] + bv.z; o[e][3] = acc[e][3] + bv.w;
        float4 ov = {o[e][0], o[e][1], o[e][2], o[e][3]};
        *(float4*)&Hout[(size_t)(m0 + ty * 4 + e) * 640 + n0 + tx * 4] = ov;
    }
    // transpose epilogue -> hT bf16
    __syncthreads();
#pragma unroll
    for (int e = 0; e < 4; ++e)
#pragma unroll
        for (int q = 0; q < 4; ++q)
            TT[tx * 4 + q][ty * 4 + e] = f2bf(o[e][q]);
    __syncthreads();
    const int b = m0 >> 8, jbase = m0 & 255, r = n0 >> 7, cbase = n0 & 127;
#pragma unroll
    for (int p = 0; p < 8; ++p) {
        int nl = p * 8 + (t >> 5);
        int ml = (t & 31) * 2;
        unsigned v = *(const unsigned*)&TT[nl][ml];
        *(unsigned*)&hT[(size_t)(b * 128 + cbase + nl) * 1280 + r * 256 + jbase + ml] = v;
    }
}

// ---------------- src[b,n,r] = h . a[r,:C] ; dst[b,n,r] = h . a[r,C:] ----------------
__global__ __launch_bounds__(256) void k_srcdst(const float* __restrict__ h,
                                                const float* __restrict__ a,
                                                float* __restrict__ src,
                                                float* __restrict__ dst) {
    int wid = threadIdx.x >> 6, lane = threadIdx.x & 63;
    int row = blockIdx.x * 4 + wid;                  // b*N + n
    const float* hr = h + (size_t)row * 640;
#pragma unroll
    for (int r = 0; r < 5; ++r) {
        float h0 = hr[r * 128 + lane], h1 = hr[r * 128 + 64 + lane];
        float s1 = h0 * a[r * 256 + lane] + h1 * a[r * 256 + 64 + lane];
        float s2 = h0 * a[r * 256 + 128 + lane] + h1 * a[r * 256 + 192 + lane];
#pragma unroll
        for (int o = 32; o > 0; o >>= 1) { s1 += __shfl_down(s1, o); s2 += __shfl_down(s2, o); }
        if (lane == 0) { src[row * 5 + r] = s1; dst[row * 5 + r] = s2; }
    }
}

// ---------------- softmax stats per (b,i): m = max, zinv = 1/sum(exp(.-m)) ----------------
__global__ __launch_bounds__(256) void k_stats(const float* __restrict__ src,
                                               const float* __restrict__ dst,
                                               const unsigned char* __restrict__ maskp,
                                               float* __restrict__ m_arr,
                                               float* __restrict__ zinv) {
    int row = blockIdx.x;                            // b*N + i
    int t = threadIdx.x;                             // j
    int b = row >> 8;
    float sv[5];
    {
        const float* sp = src + (size_t)row * 5;
#pragma unroll
        for (int r = 0; r < 5; ++r) sv[r] = sp[r];
    }
    const float* dp = dst + ((size_t)(b << 8) + t) * 5;
    unsigned mk = maskp[((size_t)row << 8) + t];
    float v[5];
#pragma unroll
    for (int r = 0; r < 5; ++r) {
        float xx = lrelu(sv[r] + dp[r]);
        v[r] = ((mk >> r) & 1) ? xx : NEGF;
    }
    float lmax = v[0];
#pragma unroll
    for (int r = 1; r < 5; ++r) lmax = fmaxf(lmax, v[r]);

    __shared__ float red[4], red2[4];
#pragma unroll
    for (int o = 32; o > 0; o >>= 1) lmax = fmaxf(lmax, __shfl_down(lmax, o));
    if ((t & 63) == 0) red[t >> 6] = lmax;
    __syncthreads();
    float m = fmaxf(fmaxf(red[0], red[1]), fmaxf(red[2], red[3]));

    float lsum = 0.f;
#pragma unroll
    for (int r = 0; r < 5; ++r) lsum += __expf(v[r] - m);
#pragma unroll
    for (int o = 32; o > 0; o >>= 1) lsum += __shfl_down(lsum, o);
    if ((t & 63) == 0) red2[t >> 6] = lsum;
    __syncthreads();
    if (t == 0) {
        float Z = red2[0] + red2[1] + red2[2] + red2[3];
        m_arr[row] = m;
        zinv[row] = 1.0f / Z;
    }
}

// ---------------- MFMA aggregation: out[b,i,c] += sum_{j,r in window} P * H ----------------
// grid (4 j-splits of 64, 8 i-tiles of 32, 32 b); 256 threads = 4 waves
// Ps[i][r*64+jl] bf16 in LDS; B-frags read directly from hT (L2).
__global__ __launch_bounds__(256) void k_agg(const unsigned short* __restrict__ hT,
                                             const float* __restrict__ src,
                                             const float* __restrict__ dst,
                                             const unsigned char* __restrict__ maskp,
                                             const float* __restrict__ m_arr,
                                             const float* __restrict__ zinv,
                                             float* __restrict__ out) {
    __shared__ unsigned short Ps[32][328];   // stride 328 -> 656B rows: +4 banks/row
    __shared__ float Ss[160], Ds[320], Ms[32], Zs[32];
    const int t = threadIdx.x;
    const int js = blockIdx.x, itile = blockIdx.y, b = blockIdx.z;
    const int i0 = itile * 32, j0 = js * 64;
    const int ib = b * 256 + i0;

    if (t < 160) Ss[t] = src[(size_t)ib * 5 + t];
    for (int idx = t; idx < 320; idx += 256) Ds[idx] = dst[(size_t)(b * 256 + j0) * 5 + idx];
    if (t < 32) { Ms[t] = m_arr[ib + t]; Zs[t] = zinv[ib + t]; }
    __syncthreads();

    // P generation: 32 i x 64 j pairs, 5 r each
    for (int p = t; p < 2048; p += 256) {
        int i = p >> 6, jl = p & 63;
        unsigned mk = maskp[((size_t)(ib + i) << 8) + j0 + jl];
        float m = Ms[i], z = Zs[i];
#pragma unroll
        for (int r = 0; r < 5; ++r) {
            float v = lrelu(Ss[i * 5 + r] + Ds[jl * 5 + r]);
            v = ((mk >> r) & 1) ? v : NEGF;
            Ps[i][r * 64 + jl] = f2bf(__expf(v - m) * z);
        }
    }
    __syncthreads();

    // MFMA: wave w -> i-half (w&1), c-half (w>>1); K = 320 in 10 steps of 32
    const int w = t >> 6, lane = t & 63;
    const int ih = w & 1, ch = w >> 1;
    const int rowl = lane & 15, koff = (lane >> 4) * 8;
    const unsigned short* hTb = hT + (size_t)b * 128 * 1280;
    f32x4 acc[4] = {};
    const unsigned short* prow = &Ps[ih * 16 + rowl][koff];
    const unsigned short* bbase0 = hTb + (size_t)(ch * 64 + rowl) * 1280 + j0 + koff;
#pragma unroll
    for (int s = 0; s < 10; ++s) {
        const int kk0 = s * 32;
        const int goff = (kk0 >> 6) * 256 + (kk0 & 63);   // r*256 + jl
        bf16x8 af = *(const bf16x8*)(prow + kk0);
#pragma unroll
        for (int ct = 0; ct < 4; ++ct) {
            bf16x8 bfv = *(const bf16x8*)(bbase0 + (size_t)ct * 16 * 1280 + goff);
            acc[ct] = __builtin_amdgcn_mfma_f32_16x16x32_bf16(af, bfv, acc[ct], 0, 0, 0);
        }
    }
    const int irow = ib + ih * 16 + (lane >> 4) * 4;
#pragma unroll
    for (int ct = 0; ct < 4; ++ct) {
        int c = ch * 64 + ct * 16 + (lane & 15);
#pragma unroll
        for (int reg = 0; reg < 4; ++reg)
            atomicAdd(&out[(size_t)(irow + reg) * 128 + c], acc[ct][reg]);
    }
}

// ---------------- pooling: feats[b] = [mean_n h3, max_n h3] ----------------
__global__ __launch_bounds__(128) void k_pool(const float* __restrict__ h3,
                                              float* __restrict__ feats) {
    int b = blockIdx.x, c = threadIdx.x;
    float sm = 0.f, mx = -3.4e38f;
    for (int n = 0; n < NN; ++n) {
        float v = h3[((size_t)(b * NN + n)) * 128 + c];
        sm += v; mx = fmaxf(mx, v);
    }
    feats[b * 256 + c] = sm * (1.f / NN);
    feats[b * 256 + 128 + c] = mx;
}

// ---------------- MLP layer 1 (k-split partials): part[ks,b,o] ----------------
__global__ __launch_bounds__(256) void k_mlp1(const float* __restrict__ x,
                                              const float* __restrict__ feats,
                                              const float* __restrict__ We1,
                                              float* __restrict__ part) {
    int ks = blockIdx.x;                 // 0..3, k range [ks*320, ks*320+320)
    int b = blockIdx.y;
    int o = threadIdx.x;
    __shared__ float zs[320];
    for (int k = o; k < 320; k += 256) {
        int gk = ks * 320 + k;
        zs[k] = (gk < 1024) ? x[b * 1024 + gk] : feats[b * 256 + gk - 1024];
    }
    __syncthreads();
    float s = 0.f;
    for (int k = 0; k < 320; ++k) s += zs[k] * We1[(size_t)(ks * 320 + k) * 256 + o];
    part[(size_t)(ks * 32 + b) * 256 + o] = s;
}

// ---------------- MLP layers 2+3 ----------------
__global__ __launch_bounds__(256) void k_mlp23(const float* __restrict__ part,
                                               const float* __restrict__ be1,
                                               const float* __restrict__ We2,
                                               const float* __restrict__ be2,
                                               const float* __restrict__ We3,
                                               const float* __restrict__ be3,
                                               float* __restrict__ out) {
    int b = blockIdx.x, t = threadIdx.x;
    __shared__ float zs[256], z2s[32];
    float s = part[(size_t)(0 + b) * 256 + t] + part[(size_t)(32 + b) * 256 + t] +
              part[(size_t)(64 + b) * 256 + t] + part[(size_t)(96 + b) * 256 + t] + be1[t];
    zs[t] = lrelu(s);
    __syncthreads();
    if (t < 32) {
        float s2 = be2[t];
        for (int k = 0; k < 256; ++k) s2 += zs[k] * We2[k * 32 + t];
        z2s[t] = lrelu(s2);
    }
    __syncthreads();
    if (t == 0) {
        float s3 = be3[0];
#pragma unroll
        for (int k = 0; k < 32; ++k) s3 += z2s[k] * We3[k];
        out[b] = s3;
    }
}

// ---------------- workspace layout ----------------
constexpr size_t O_MASK = 0;                                   // 2,097,152 B
constexpr size_t O_H    = 2097152;                             // 8192*640*4
constexpr size_t O_SRC  = O_H + 8192ull * 640 * 4;
constexpr size_t O_DST  = O_SRC + 8192ull * 5 * 4;
constexpr size_t O_M    = O_DST + 8192ull * 5 * 4;
constexpr size_t O_Z    = O_M + 8192ull * 4;
constexpr size_t O_OUTA = O_Z + 8192ull * 4;
constexpr size_t O_OUTB = O_OUTA + 8192ull * 128 * 4;
constexpr size_t O_FEAT = O_OUTB + 8192ull * 128 * 4;
constexpr size_t O_PART = O_FEAT + 32ull * 256 * 4;
constexpr size_t O_HT   = O_PART + 128ull * 256 * 4;           // hT bf16: 32*128*1280*2 = 10.5 MB

extern "C" void kernel_launch(void* const* d_in, const int* in_sizes, int n_in,
                              void* d_out, int out_size, void* d_ws, size_t ws_size,
                              hipStream_t stream) {
    const float* x       = (const float*)d_in[0];
    const float* y_atoms = (const float*)d_in[1];
    const int*   y_bonds = (const int*)d_in[2];
    const float* W1 = (const float*)d_in[3];
    const float* b1 = (const float*)d_in[4];
    const float* a1 = (const float*)d_in[5];
    const float* W2 = (const float*)d_in[6];
    const float* b2 = (const float*)d_in[7];
    const float* a2 = (const float*)d_in[8];
    const float* W3 = (const float*)d_in[9];
    const float* b3 = (const float*)d_in[10];
    const float* a3 = (const float*)d_in[11];
    const float* We1 = (const float*)d_in[12];
    const float* be1 = (const float*)d_in[13];
    const float* We2 = (const float*)d_in[14];
    const float* be2 = (const float*)d_in[15];
    const float* We3 = (const float*)d_in[16];
    const float* be3 = (const float*)d_in[17];
    float* out = (float*)d_out;

    char* ws = (char*)d_ws;
    unsigned char* maskp = (unsigned char*)(ws + O_MASK);
    float* h    = (float*)(ws + O_H);
    float* srcb = (float*)(ws + O_SRC);
    float* dstb = (float*)(ws + O_DST);
    float* marr = (float*)(ws + O_M);
    float* zinv = (float*)(ws + O_Z);
    float* outA = (float*)(ws + O_OUTA);
    float* outB = (float*)(ws + O_OUTB);
    float* feats = (float*)(ws + O_FEAT);
    float* part  = (float*)(ws + O_PART);
    unsigned short* hT = (unsigned short*)(ws + O_HT);

    dim3 blk(256);
    k_pack_mask<<<8192, blk, 0, stream>>>(y_bonds, maskp);

    // layer 1 (K=64, no leaky on input)
    k_gemm_h<64, false><<<dim3(10, 128), blk, 0, stream>>>(y_atoms, W1, b1, h, hT);
    k_srcdst<<<2048, blk, 0, stream>>>(h, a1, srcb, dstb);
    k_stats<<<8192, blk, 0, stream>>>(srcb, dstb, maskp, marr, zinv);
    hipMemsetAsync(outA, 0, 8192ull * 128 * 4, stream);
    k_agg<<<dim3(4, 8, 32), blk, 0, stream>>>(hT, srcb, dstb, maskp, marr, zinv, outA);

    // layer 2 (K=128, leaky on input)
    k_gemm_h<128, true><<<dim3(10, 128), blk, 0, stream>>>(outA, W2, b2, h, hT);
    k_srcdst<<<2048, blk, 0, stream>>>(h, a2, srcb, dstb);
    k_stats<<<8192, blk, 0, stream>>>(srcb, dstb, maskp, marr, zinv);
    hipMemsetAsync(outB, 0, 8192ull * 128 * 4, stream);
    k_agg<<<dim3(4, 8, 32), blk, 0, stream>>>(hT, srcb, dstb, maskp, marr, zinv, outB);

    // layer 3 (K=128, leaky on input)
    k_gemm_h<128, true><<<dim3(10, 128), blk, 0, stream>>>(outB, W3, b3, h, hT);
    k_srcdst<<<2048, blk, 0, stream>>>(h, a3, srcb, dstb);
    k_stats<<<8192, blk, 0, stream>>>(srcb, dstb, maskp, marr, zinv);
    hipMemsetAsync(outA, 0, 8192ull * 128 * 4, stream);
    k_agg<<<dim3(4, 8, 32), blk, 0, stream>>>(hT, srcb, dstb, maskp, marr, zinv, outA);

    // pooling + MLP
    k_pool<<<32, dim3(128), 0, stream>>>(outA, feats);
    k_mlp1<<<dim3(4, 32), blk, 0, stream>>>(x, feats, We1, part);
    k_mlp23<<<32, blk, 0, stream>>>(part, be1, We2, be2, We3, be3, out);
}

// Round 3
// 339.855 us; speedup vs baseline: 2.0681x; 1.0905x over previous
//
#include <hip/hip_runtime.h>
#include <cstddef>

#define BB 32
#define NN 256
#define RR 5
#define NEGF (-9.0e15f)

typedef __attribute__((ext_vector_type(8))) short bf16x8;
typedef __attribute__((ext_vector_type(4))) float f32x4;

__device__ __forceinline__ float lrelu(float x) { return x >= 0.f ? x : 0.2f * x; }
// RNE float -> bf16
__device__ __forceinline__ unsigned short f2bf(float x) {
    unsigned u = __float_as_uint(x);
    u += 0x7FFFu + ((u >> 16) & 1u);
    return (unsigned short)(u >> 16);
}

// =======================================================================================
// gemm_h: per layer, h = A(8192 x K) @ W(K x 640) + bias (MFMA bf16, fp32 accum).
// Emits: hT bf16 [b*128+c][r*256+j]  and  src/dst partial dots (2 halves, non-atomic).
// SUMPARTS: A = sum of 4 j-split partials (layers 2/3), with leaky.
// grid (10 n-tiles of 64, 128 m-tiles of 64), 256 threads = 4 waves.
// =======================================================================================
template <int K, bool LEAKY, bool SUMPARTS>
__global__ __launch_bounds__(256) void k_gemm_h(const float* __restrict__ Adir,
                                                const float* __restrict__ Aparts,
                                                const float* __restrict__ W,
                                                const float* __restrict__ bias,
                                                const float* __restrict__ avec,
                                                float* __restrict__ srcp,
                                                float* __restrict__ dstp,
                                                unsigned short* __restrict__ hT) {
    __shared__ unsigned short As[64][K + 8];   // [m][k], +8 pad -> 4-bank row shift
    __shared__ unsigned short WT[64][K + 8];   // [n][k]
    __shared__ unsigned short TT[64][72];      // [n][m] transpose staging for hT

    const int t = threadIdx.x;
    const int n0 = blockIdx.x * 64, m0 = blockIdx.y * 64;

    // ---- stage A -> bf16 LDS [m][k] ----
    for (int idx = t; idx < 64 * (K / 4); idx += 256) {
        int m = idx / (K / 4), kk = (idx % (K / 4)) * 4;
        float4 v;
        if (SUMPARTS) {
            size_t off = (size_t)(m0 + m) * K + kk;
            float4 p0 = *(const float4*)&Aparts[off];
            float4 p1 = *(const float4*)&Aparts[off + 1048576];   // 8192*128
            float4 p2 = *(const float4*)&Aparts[off + 2097152];
            float4 p3 = *(const float4*)&Aparts[off + 3145728];
            v.x = p0.x + p1.x + p2.x + p3.x; v.y = p0.y + p1.y + p2.y + p3.y;
            v.z = p0.z + p1.z + p2.z + p3.z; v.w = p0.w + p1.w + p2.w + p3.w;
        } else {
            v = *(const float4*)&Adir[(size_t)(m0 + m) * K + kk];
        }
        if (LEAKY) { v.x = lrelu(v.x); v.y = lrelu(v.y); v.z = lrelu(v.z); v.w = lrelu(v.w); }
        As[m][kk] = f2bf(v.x); As[m][kk + 1] = f2bf(v.y);
        As[m][kk + 2] = f2bf(v.z); As[m][kk + 3] = f2bf(v.w);
    }
    // ---- stage W -> bf16 LDS transposed [n][k] ----
    for (int idx = t; idx < 64 * (K / 4); idx += 256) {
        int k = idx / 16, n4 = (idx % 16) * 4;
        float4 v = *(const float4*)&W[(size_t)k * 640 + n0 + n4];
        WT[n4][k] = f2bf(v.x); WT[n4 + 1][k] = f2bf(v.y);
        WT[n4 + 2][k] = f2bf(v.z); WT[n4 + 3][k] = f2bf(v.w);
    }
    __syncthreads();

    const int w = t >> 6, lane = t & 63;
    const int colg = lane & 15, rquad = lane >> 4;
    const int koff = rquad * 8;

    f32x4 acc[4] = {};
#pragma unroll
    for (int kk = 0; kk < K; kk += 32) {
        bf16x8 af = *(const bf16x8*)&As[w * 16 + colg][kk + koff];
#pragma unroll
        for (int ct = 0; ct < 4; ++ct) {
            bf16x8 bfv = *(const bf16x8*)&WT[ct * 16 + colg][kk + koff];
            acc[ct] = __builtin_amdgcn_mfma_f32_16x16x32_bf16(af, bfv, acc[ct], 0, 0, 0);
        }
    }

    // ---- epilogue: bias, src/dst partial dots, TT quantize ----
    const int r = n0 >> 7, chalf = n0 & 127;
    float val[4][4];
    float ssum[4] = {0.f, 0.f, 0.f, 0.f}, dsum[4] = {0.f, 0.f, 0.f, 0.f};
#pragma unroll
    for (int ct = 0; ct < 4; ++ct) {
        int cg = chalf + ct * 16 + colg;
        float bv = bias[n0 + ct * 16 + colg];
        float asr = avec[r * 256 + cg];
        float ads = avec[r * 256 + 128 + cg];
#pragma unroll
        for (int reg = 0; reg < 4; ++reg) {
            float v = acc[ct][reg] + bv;
            val[ct][reg] = v;
            ssum[reg] += v * asr;
            dsum[reg] += v * ads;
        }
    }
#pragma unroll
    for (int mk = 1; mk < 16; mk <<= 1)
#pragma unroll
        for (int reg = 0; reg < 4; ++reg) {
            ssum[reg] += __shfl_xor(ssum[reg], mk);
            dsum[reg] += __shfl_xor(dsum[reg], mk);
        }
    if (colg == 0) {
        int half = (n0 >> 6) & 1;
#pragma unroll
        for (int reg = 0; reg < 4; ++reg) {
            int row = m0 + w * 16 + rquad * 4 + reg;
            srcp[half * 40960 + row * 5 + r] = ssum[reg];
            dstp[half * 40960 + row * 5 + r] = dsum[reg];
        }
    }
#pragma unroll
    for (int ct = 0; ct < 4; ++ct)
#pragma unroll
        for (int reg = 0; reg < 4; ++reg)
            TT[ct * 16 + colg][w * 16 + rquad * 4 + reg] = f2bf(val[ct][reg]);
    __syncthreads();

    // ---- write hT rows (c over this block's 64 n, j over this block's 64 m) ----
    const int b = m0 >> 8, jb = m0 & 255;
    {
        int nl = t >> 2, mlq = (t & 3) * 16;
        unsigned short* dstg = &hT[(size_t)(b * 128 + chalf + nl) * 1280 + r * 256 + jb + mlq];
        float4 v0 = *(const float4*)&TT[nl][mlq];
        float4 v1 = *(const float4*)&TT[nl][mlq + 8];
        *(float4*)dstg = v0;
        *(float4*)(dstg + 8) = v1;
    }
}

// =======================================================================================
// softmax stats per (b,i). PACK variant reads y_bonds directly and emits maskp.
// =======================================================================================
template <bool PACK>
__global__ __launch_bounds__(256) void k_stats(const int* __restrict__ bonds,
                                               const float* __restrict__ srcp,
                                               const float* __restrict__ dstp,
                                               unsigned char* __restrict__ maskp,
                                               float* __restrict__ m_arr,
                                               float* __restrict__ zinv) {
    int row = blockIdx.x;                            // b*N + i
    int t = threadIdx.x;                             // j
    int b = row >> 8;
    float sv[5];
#pragma unroll
    for (int r = 0; r < 5; ++r)
        sv[r] = srcp[(size_t)row * 5 + r] + srcp[40960 + (size_t)row * 5 + r];

    const float* dp0 = dstp + ((size_t)(b << 8) + t) * 5;
    const float* dp1 = dp0 + 40960;
    unsigned mk;
    if (PACK) {
        const int* p = bonds + (((size_t)row << 8) + t) * 5;
        mk = 0;
#pragma unroll
        for (int r = 0; r < 5; ++r) mk |= (p[r] == 1) ? (1u << r) : 0u;
        maskp[((size_t)row << 8) + t] = (unsigned char)mk;
    } else {
        mk = maskp[((size_t)row << 8) + t];
    }
    float v[5];
#pragma unroll
    for (int r = 0; r < 5; ++r) {
        float xx = lrelu(sv[r] + dp0[r] + dp1[r]);
        v[r] = ((mk >> r) & 1) ? xx : NEGF;
    }
    float lmax = v[0];
#pragma unroll
    for (int r = 1; r < 5; ++r) lmax = fmaxf(lmax, v[r]);

    __shared__ float red[4], red2[4];
#pragma unroll
    for (int o = 32; o > 0; o >>= 1) lmax = fmaxf(lmax, __shfl_down(lmax, o));
    if ((t & 63) == 0) red[t >> 6] = lmax;
    __syncthreads();
    float m = fmaxf(fmaxf(red[0], red[1]), fmaxf(red[2], red[3]));

    float lsum = 0.f;
#pragma unroll
    for (int r = 0; r < 5; ++r) lsum += __expf(v[r] - m);
#pragma unroll
    for (int o = 32; o > 0; o >>= 1) lsum += __shfl_down(lsum, o);
    if ((t & 63) == 0) red2[t >> 6] = lsum;
    __syncthreads();
    if (t == 0) {
        float Z = red2[0] + red2[1] + red2[2] + red2[3];
        m_arr[row] = m;
        zinv[row] = 1.0f / Z;
    }
}

// =======================================================================================
// MFMA aggregation -> j-split partials aggP[js][row][c] (no atomics).
// grid (4 j-splits of 64, 8 i-tiles of 32, 32 b); 256 threads = 4 waves.
// =======================================================================================
__global__ __launch_bounds__(256) void k_agg(const unsigned short* __restrict__ hT,
                                             const float* __restrict__ srcp,
                                             const float* __restrict__ dstp,
                                             const unsigned char* __restrict__ maskp,
                                             const float* __restrict__ m_arr,
                                             const float* __restrict__ zinv,
                                             float* __restrict__ aggP) {
    __shared__ unsigned short Ps[32][328];
    __shared__ float Ss[160], Ds[320], Ms[32], Zs[32];
    const int t = threadIdx.x;
    const int js = blockIdx.x, itile = blockIdx.y, b = blockIdx.z;
    const int i0 = itile * 32, j0 = js * 64;
    const int ib = b * 256 + i0;

    if (t < 160) Ss[t] = srcp[(size_t)ib * 5 + t] + srcp[40960 + (size_t)ib * 5 + t];
    for (int idx = t; idx < 320; idx += 256) {
        size_t o = (size_t)(b * 256 + j0) * 5 + idx;
        Ds[idx] = dstp[o] + dstp[40960 + o];
    }
    if (t < 32) { Ms[t] = m_arr[ib + t]; Zs[t] = zinv[ib + t]; }
    __syncthreads();

    for (int p = t; p < 2048; p += 256) {
        int i = p >> 6, jl = p & 63;
        unsigned mk = maskp[((size_t)(ib + i) << 8) + j0 + jl];
        float m = Ms[i], z = Zs[i];
#pragma unroll
        for (int r = 0; r < 5; ++r) {
            float v = lrelu(Ss[i * 5 + r] + Ds[jl * 5 + r]);
            v = ((mk >> r) & 1) ? v : NEGF;
            Ps[i][r * 64 + jl] = f2bf(__expf(v - m) * z);
        }
    }
    __syncthreads();

    const int w = t >> 6, lane = t & 63;
    const int ih = w & 1, ch = w >> 1;
    const int rowl = lane & 15, koff = (lane >> 4) * 8;
    const unsigned short* hTb = hT + (size_t)b * 128 * 1280;
    f32x4 acc[4] = {};
    const unsigned short* prow = &Ps[ih * 16 + rowl][koff];
    const unsigned short* bbase0 = hTb + (size_t)(ch * 64 + rowl) * 1280 + j0 + koff;
#pragma unroll
    for (int s = 0; s < 10; ++s) {
        const int kk0 = s * 32;
        const int goff = (kk0 >> 6) * 256 + (kk0 & 63);   // r*256 + jl
        bf16x8 af = *(const bf16x8*)(prow + kk0);
#pragma unroll
        for (int ct = 0; ct < 4; ++ct) {
            bf16x8 bfv = *(const bf16x8*)(bbase0 + (size_t)ct * 16 * 1280 + goff);
            acc[ct] = __builtin_amdgcn_mfma_f32_16x16x32_bf16(af, bfv, acc[ct], 0, 0, 0);
        }
    }
    float* op = aggP + (size_t)js * 1048576;   // 8192*128
    const int irow = ib + ih * 16 + (lane >> 4) * 4;
#pragma unroll
    for (int ct = 0; ct < 4; ++ct) {
        int c = ch * 64 + ct * 16 + (lane & 15);
#pragma unroll
        for (int reg = 0; reg < 4; ++reg)
            op[(size_t)(irow + reg) * 128 + c] = acc[ct][reg];
    }
}

// ---------------- pooling over summed partials ----------------
__global__ __launch_bounds__(128) void k_pool(const float* __restrict__ aggP,
                                              float* __restrict__ feats) {
    int b = blockIdx.x, c = threadIdx.x;
    float sm = 0.f, mx = -3.4e38f;
    for (int n = 0; n < NN; ++n) {
        size_t o = ((size_t)(b * NN + n)) * 128 + c;
        float v = aggP[o] + aggP[o + 1048576] + aggP[o + 2097152] + aggP[o + 3145728];
        sm += v; mx = fmaxf(mx, v);
    }
    feats[b * 256 + c] = sm * (1.f / NN);
    feats[b * 256 + 128 + c] = mx;
}

// ---------------- MLP layer 1 (k-split partials): part[ks,b,o] ----------------
__global__ __launch_bounds__(256) void k_mlp1(const float* __restrict__ x,
                                              const float* __restrict__ feats,
                                              const float* __restrict__ We1,
                                              float* __restrict__ part) {
    int ks = blockIdx.x;
    int b = blockIdx.y;
    int o = threadIdx.x;
    __shared__ float zs[320];
    for (int k = o; k < 320; k += 256) {
        int gk = ks * 320 + k;
        zs[k] = (gk < 1024) ? x[b * 1024 + gk] : feats[b * 256 + gk - 1024];
    }
    __syncthreads();
    float s = 0.f;
    for (int k = 0; k < 320; ++k) s += zs[k] * We1[(size_t)(ks * 320 + k) * 256 + o];
    part[(size_t)(ks * 32 + b) * 256 + o] = s;
}

// ---------------- MLP layers 2+3 ----------------
__global__ __launch_bounds__(256) void k_mlp23(const float* __restrict__ part,
                                               const float* __restrict__ be1,
                                               const float* __restrict__ We2,
                                               const float* __restrict__ be2,
                                               const float* __restrict__ We3,
                                               const float* __restrict__ be3,
                                               float* __restrict__ out) {
    int b = blockIdx.x, t = threadIdx.x;
    __shared__ float zs[256], z2s[32];
    float s = part[(size_t)(0 + b) * 256 + t] + part[(size_t)(32 + b) * 256 + t] +
              part[(size_t)(64 + b) * 256 + t] + part[(size_t)(96 + b) * 256 + t] + be1[t];
    zs[t] = lrelu(s);
    __syncthreads();
    if (t < 32) {
        float s2 = be2[t];
        for (int k = 0; k < 256; ++k) s2 += zs[k] * We2[k * 32 + t];
        z2s[t] = lrelu(s2);
    }
    __syncthreads();
    if (t == 0) {
        float s3 = be3[0];
#pragma unroll
        for (int k = 0; k < 32; ++k) s3 += z2s[k] * We3[k];
        out[b] = s3;
    }
}

// ---------------- workspace layout ----------------
constexpr size_t O_MASK = 0;                                   // 2 MB
constexpr size_t O_SRCP = 2097152;                             // 2 halves x 40960 floats
constexpr size_t O_DSTP = O_SRCP + 2ull * 40960 * 4;
constexpr size_t O_M    = O_DSTP + 2ull * 40960 * 4;
constexpr size_t O_Z    = O_M + 8192ull * 4;
constexpr size_t O_AGG  = O_Z + 8192ull * 4;                   // 4 x 8192 x 128 fp32 = 16.8 MB
constexpr size_t O_FEAT = O_AGG + 4ull * 1048576 * 4;
constexpr size_t O_PART = O_FEAT + 32ull * 256 * 4;
constexpr size_t O_HT   = O_PART + 128ull * 256 * 4;           // hT bf16: 10.5 MB

extern "C" void kernel_launch(void* const* d_in, const int* in_sizes, int n_in,
                              void* d_out, int out_size, void* d_ws, size_t ws_size,
                              hipStream_t stream) {
    const float* x       = (const float*)d_in[0];
    const float* y_atoms = (const float*)d_in[1];
    const int*   y_bonds = (const int*)d_in[2];
    const float* W1 = (const float*)d_in[3];
    const float* b1 = (const float*)d_in[4];
    const float* a1 = (const float*)d_in[5];
    const float* W2 = (const float*)d_in[6];
    const float* b2 = (const float*)d_in[7];
    const float* a2 = (const float*)d_in[8];
    const float* W3 = (const float*)d_in[9];
    const float* b3 = (const float*)d_in[10];
    const float* a3 = (const float*)d_in[11];
    const float* We1 = (const float*)d_in[12];
    const float* be1 = (const float*)d_in[13];
    const float* We2 = (const float*)d_in[14];
    const float* be2 = (const float*)d_in[15];
    const float* We3 = (const float*)d_in[16];
    const float* be3 = (const float*)d_in[17];
    float* out = (float*)d_out;

    char* ws = (char*)d_ws;
    unsigned char* maskp = (unsigned char*)(ws + O_MASK);
    float* srcp = (float*)(ws + O_SRCP);
    float* dstp = (float*)(ws + O_DSTP);
    float* marr = (float*)(ws + O_M);
    float* zinv = (float*)(ws + O_Z);
    float* aggP = (float*)(ws + O_AGG);
    float* feats = (float*)(ws + O_FEAT);
    float* part  = (float*)(ws + O_PART);
    unsigned short* hT = (unsigned short*)(ws + O_HT);

    dim3 blk(256);

    // layer 1
    k_gemm_h<64, false, false><<<dim3(10, 128), blk, 0, stream>>>(
        y_atoms, nullptr, W1, b1, a1, srcp, dstp, hT);
    k_stats<true><<<8192, blk, 0, stream>>>(y_bonds, srcp, dstp, maskp, marr, zinv);
    k_agg<<<dim3(4, 8, 32), blk, 0, stream>>>(hT, srcp, dstp, maskp, marr, zinv, aggP);

    // layer 2
    k_gemm_h<128, true, true><<<dim3(10, 128), blk, 0, stream>>>(
        nullptr, aggP, W2, b2, a2, srcp, dstp, hT);
    k_stats<false><<<8192, blk, 0, stream>>>(y_bonds, srcp, dstp, maskp, marr, zinv);
    k_agg<<<dim3(4, 8, 32), blk, 0, stream>>>(hT, srcp, dstp, maskp, marr, zinv, aggP);

    // layer 3
    k_gemm_h<128, true, true><<<dim3(10, 128), blk, 0, stream>>>(
        nullptr, aggP, W3, b3, a3, srcp, dstp, hT);
    k_stats<false><<<8192, blk, 0, stream>>>(y_bonds, srcp, dstp, maskp, marr, zinv);
    k_agg<<<dim3(4, 8, 32), blk, 0, stream>>>(hT, srcp, dstp, maskp, marr, zinv, aggP);

    // pooling + MLP
    k_pool<<<32, dim3(128), 0, stream>>>(aggP, feats);
    k_mlp1<<<dim3(4, 32), blk, 0, stream>>>(x, feats, We1, part);
    k_mlp23<<<32, blk, 0, stream>>>(part, be1, We2, be2, We3, be3, out);
}

// Round 4
// 331.469 us; speedup vs baseline: 2.1204x; 1.0253x over previous
//
#include <hip/hip_runtime.h>
#include <cstddef>

#define BB 32
#define NN 256
#define RR 5
#define NEGF (-9.0e15f)

typedef __attribute__((ext_vector_type(8))) short bf16x8;
typedef __attribute__((ext_vector_type(4))) float f32x4;

__device__ __forceinline__ float lrelu(float x) { return x >= 0.f ? x : 0.2f * x; }
// RNE float -> bf16
__device__ __forceinline__ unsigned short f2bf(float x) {
    unsigned u = __float_as_uint(x);
    u += 0x7FFFu + ((u >> 16) & 1u);
    return (unsigned short)(u >> 16);
}

// =======================================================================================
// k_prepw: one-time transpose W (K x 640 fp32) -> WT (640 x K bf16) for all 3 layers.
// 30 blocks: layer = blk/10, n-tile of 64 = blk%10.
// =======================================================================================
__global__ __launch_bounds__(256) void k_prepw(const float* __restrict__ W1,
                                               const float* __restrict__ W2,
                                               const float* __restrict__ W3,
                                               unsigned short* __restrict__ WT1,
                                               unsigned short* __restrict__ WT2,
                                               unsigned short* __restrict__ WT3) {
    int blk = blockIdx.x;
    int layer = blk / 10, nt = blk % 10;
    const float* W;
    unsigned short* WT;
    int K;
    if (layer == 0)      { W = W1; WT = WT1; K = 64; }
    else if (layer == 1) { W = W2; WT = WT2; K = 128; }
    else                 { W = W3; WT = WT3; K = 128; }
    int n = nt * 64 + (threadIdx.x & 63);
    for (int kg = (int)(threadIdx.x >> 6); kg < K / 8; kg += 4) {
        bf16x8 v;
#pragma unroll
        for (int e = 0; e < 8; ++e) v[e] = (short)f2bf(W[(size_t)(kg * 8 + e) * 640 + n]);
        *(bf16x8*)&WT[(size_t)n * K + kg * 8] = v;
    }
}

// =======================================================================================
// gemm_h: h = A(8192 x K) @ W(K x 640) + bias, MFMA bf16 (fp32 accum), NO LDS staging:
//  - A fragments read from global fp32 (SUMPARTS: sum of 4 aggP partials + leaky)
//  - B fragments read from pre-transposed bf16 WT[n][k] (L1/L2 resident)
// Emits hT bf16 [b*128+c][r*256+j] (via LDS transpose) and src/dst partial dots.
// grid (10 n-tiles of 64, 128 m-tiles of 64), 256 threads = 4 waves.
// =======================================================================================
template <int K, bool LEAKY, bool SUMPARTS>
__global__ __launch_bounds__(256) void k_gemm_h(const float* __restrict__ Adir,
                                                const float* __restrict__ Aparts,
                                                const unsigned short* __restrict__ WTg,
                                                const float* __restrict__ bias,
                                                const float* __restrict__ avec,
                                                float* __restrict__ srcp,
                                                float* __restrict__ dstp,
                                                unsigned short* __restrict__ hT) {
    __shared__ unsigned short TT[64][72];   // [n][m] transpose staging (stride 72: 16B-aligned rows)

    const int t = threadIdx.x;
    const int n0 = blockIdx.x * 64, m0 = blockIdx.y * 64;
    const int w = t >> 6, lane = t & 63;
    const int colg = lane & 15, rquad = lane >> 4;
    const int m = m0 + w * 16 + colg;        // A row this lane reads
    const int koff = rquad * 8;

    f32x4 acc[4] = {};
#pragma unroll
    for (int kk = 0; kk < K; kk += 32) {
        float av[8];
        size_t off = (size_t)m * K + kk + koff;
        if (SUMPARTS) {
            float4 q0 = *(const float4*)&Aparts[off];
            float4 q1 = *(const float4*)&Aparts[off + 4];
            float4 r0 = *(const float4*)&Aparts[off + 1048576];
            float4 r1 = *(const float4*)&Aparts[off + 1048576 + 4];
            float4 s0 = *(const float4*)&Aparts[off + 2097152];
            float4 s1 = *(const float4*)&Aparts[off + 2097152 + 4];
            float4 u0 = *(const float4*)&Aparts[off + 3145728];
            float4 u1 = *(const float4*)&Aparts[off + 3145728 + 4];
            av[0] = q0.x + r0.x + s0.x + u0.x; av[1] = q0.y + r0.y + s0.y + u0.y;
            av[2] = q0.z + r0.z + s0.z + u0.z; av[3] = q0.w + r0.w + s0.w + u0.w;
            av[4] = q1.x + r1.x + s1.x + u1.x; av[5] = q1.y + r1.y + s1.y + u1.y;
            av[6] = q1.z + r1.z + s1.z + u1.z; av[7] = q1.w + r1.w + s1.w + u1.w;
        } else {
            float4 q0 = *(const float4*)&Adir[off];
            float4 q1 = *(const float4*)&Adir[off + 4];
            av[0] = q0.x; av[1] = q0.y; av[2] = q0.z; av[3] = q0.w;
            av[4] = q1.x; av[5] = q1.y; av[6] = q1.z; av[7] = q1.w;
        }
        bf16x8 af;
#pragma unroll
        for (int e = 0; e < 8; ++e) {
            float v = av[e];
            if (LEAKY) v = lrelu(v);
            af[e] = (short)f2bf(v);
        }
#pragma unroll
        for (int ct = 0; ct < 4; ++ct) {
            bf16x8 bfv = *(const bf16x8*)&WTg[(size_t)(n0 + ct * 16 + colg) * K + kk + koff];
            acc[ct] = __builtin_amdgcn_mfma_f32_16x16x32_bf16(af, bfv, acc[ct], 0, 0, 0);
        }
    }

    // ---- epilogue: bias, src/dst partial dots (shfl-reduce over colg), TT quantize ----
    const int r = n0 >> 7, chalf = n0 & 127;
    float val[4][4];
    float ssum[4] = {0.f, 0.f, 0.f, 0.f}, dsum[4] = {0.f, 0.f, 0.f, 0.f};
#pragma unroll
    for (int ct = 0; ct < 4; ++ct) {
        int cg = chalf + ct * 16 + colg;
        float bv = bias[n0 + ct * 16 + colg];
        float asr = avec[r * 256 + cg];
        float ads = avec[r * 256 + 128 + cg];
#pragma unroll
        for (int reg = 0; reg < 4; ++reg) {
            float v = acc[ct][reg] + bv;
            val[ct][reg] = v;
            ssum[reg] += v * asr;
            dsum[reg] += v * ads;
        }
    }
#pragma unroll
    for (int mk = 1; mk < 16; mk <<= 1)
#pragma unroll
        for (int reg = 0; reg < 4; ++reg) {
            ssum[reg] += __shfl_xor(ssum[reg], mk);
            dsum[reg] += __shfl_xor(dsum[reg], mk);
        }
    if (colg == 0) {
        int half = (n0 >> 6) & 1;
#pragma unroll
        for (int reg = 0; reg < 4; ++reg) {
            int row = m0 + w * 16 + rquad * 4 + reg;
            srcp[half * 40960 + row * 5 + r] = ssum[reg];
            dstp[half * 40960 + row * 5 + r] = dsum[reg];
        }
    }
    // TT[n][m]: 4 consecutive m per ct -> one packed 8-byte write each
#pragma unroll
    for (int ct = 0; ct < 4; ++ct) {
        unsigned lo = (unsigned)f2bf(val[ct][0]) | ((unsigned)f2bf(val[ct][1]) << 16);
        unsigned hi = (unsigned)f2bf(val[ct][2]) | ((unsigned)f2bf(val[ct][3]) << 16);
        uint2 pk; pk.x = lo; pk.y = hi;
        *(uint2*)&TT[ct * 16 + colg][w * 16 + rquad * 4] = pk;
    }
    __syncthreads();

    // ---- write hT rows (c over this block's 64 n, j over this block's 64 m) ----
    const int b = m0 >> 8, jb = m0 & 255;
    {
        int nl = t >> 2, mlq = (t & 3) * 16;
        unsigned short* dstg = &hT[(size_t)(b * 128 + chalf + nl) * 1280 + r * 256 + jb + mlq];
        float4 v0 = *(const float4*)&TT[nl][mlq];
        float4 v1 = *(const float4*)&TT[nl][mlq + 8];
        *(float4*)dstg = v0;
        *(float4*)(dstg + 8) = v1;
    }
}

// =======================================================================================
// softmax stats per (b,i). PACK variant reads y_bonds directly and emits maskp.
// =======================================================================================
template <bool PACK>
__global__ __launch_bounds__(256) void k_stats(const int* __restrict__ bonds,
                                               const float* __restrict__ srcp,
                                               const float* __restrict__ dstp,
                                               unsigned char* __restrict__ maskp,
                                               float* __restrict__ m_arr,
                                               float* __restrict__ zinv) {
    int row = blockIdx.x;                            // b*N + i
    int t = threadIdx.x;                             // j
    int b = row >> 8;
    float sv[5];
#pragma unroll
    for (int r = 0; r < 5; ++r)
        sv[r] = srcp[(size_t)row * 5 + r] + srcp[40960 + (size_t)row * 5 + r];

    const float* dp0 = dstp + ((size_t)(b << 8) + t) * 5;
    const float* dp1 = dp0 + 40960;
    unsigned mk;
    if (PACK) {
        const int* p = bonds + (((size_t)row << 8) + t) * 5;
        mk = 0;
#pragma unroll
        for (int r = 0; r < 5; ++r) mk |= (p[r] == 1) ? (1u << r) : 0u;
        maskp[((size_t)row << 8) + t] = (unsigned char)mk;
    } else {
        mk = maskp[((size_t)row << 8) + t];
    }
    float v[5];
#pragma unroll
    for (int r = 0; r < 5; ++r) {
        float xx = lrelu(sv[r] + dp0[r] + dp1[r]);
        v[r] = ((mk >> r) & 1) ? xx : NEGF;
    }
    float lmax = v[0];
#pragma unroll
    for (int r = 1; r < 5; ++r) lmax = fmaxf(lmax, v[r]);

    __shared__ float red[4], red2[4];
#pragma unroll
    for (int o = 32; o > 0; o >>= 1) lmax = fmaxf(lmax, __shfl_down(lmax, o));
    if ((t & 63) == 0) red[t >> 6] = lmax;
    __syncthreads();
    float m = fmaxf(fmaxf(red[0], red[1]), fmaxf(red[2], red[3]));

    float lsum = 0.f;
#pragma unroll
    for (int r = 0; r < 5; ++r) lsum += __expf(v[r] - m);
#pragma unroll
    for (int o = 32; o > 0; o >>= 1) lsum += __shfl_down(lsum, o);
    if ((t & 63) == 0) red2[t >> 6] = lsum;
    __syncthreads();
    if (t == 0) {
        float Z = red2[0] + red2[1] + red2[2] + red2[3];
        m_arr[row] = m;
        zinv[row] = 1.0f / Z;
    }
}

// =======================================================================================
// MFMA aggregation -> j-split partials aggP[js][row][c] (no atomics).
// Ps fragment-major: chunk p = (bk*64 + kq*16 + colg) holds P[i=ih*16+colg][k0..k0+7],
// bk = ih*10+ks, k0 = ks*32+kq*8. MFMA lane L reads chunk bk*64+L (canonical, conflict-free).
// grid (4 j-splits of 64, 8 i-tiles of 32, 32 b); 256 threads = 4 waves.
// =======================================================================================
__global__ __launch_bounds__(256) void k_agg(const unsigned short* __restrict__ hT,
                                             const float* __restrict__ srcp,
                                             const float* __restrict__ dstp,
                                             const unsigned char* __restrict__ maskp,
                                             const float* __restrict__ m_arr,
                                             const float* __restrict__ zinv,
                                             float* __restrict__ aggP) {
    __shared__ unsigned short Ps[10240];          // 20 bk x 64 chunks x 8 bf16 = 20 KB
    __shared__ float Ss[160], Ds2[320], Ms[32], Zs[32];
    const int t = threadIdx.x;
    const int js = blockIdx.x, itile = blockIdx.y, b = blockIdx.z;
    const int i0 = itile * 32, j0 = js * 64;
    const int ib = b * 256 + i0;

    if (t < 160) Ss[t] = srcp[(size_t)ib * 5 + t] + srcp[40960 + (size_t)ib * 5 + t];
    for (int idx = t; idx < 320; idx += 256) {
        int jl = idx & 63, rr = idx >> 6;
        size_t o = (size_t)(b * 256 + j0 + jl) * 5 + rr;
        Ds2[idx] = dstp[o] + dstp[40960 + o];     // Ds2[r*64 + jl]
    }
    if (t < 32) { Ms[t] = m_arr[ib + t]; Zs[t] = zinv[ib + t]; }
    __syncthreads();

    // P generation: 1280 chunks of 8, 5 per thread; one b128 LDS write per chunk
#pragma unroll
    for (int it = 0; it < 5; ++it) {
        int p = it * 256 + t;
        int colg = p & 15, kq = (p >> 4) & 3, bk = p >> 6;
        int ih = (bk >= 10) ? 1 : 0;
        int ks = bk - ih * 10;
        int i = ih * 16 + colg;
        int k0 = ks * 32 + kq * 8;
        int rr = k0 >> 6, jl0 = k0 & 63;
        uint2 mk8 = *(const uint2*)&maskp[((size_t)(ib + i) << 8) + j0 + jl0];
        float sv = Ss[i * 5 + rr];
        float m = Ms[i], z = Zs[i];
        bf16x8 pv;
#pragma unroll
        for (int e = 0; e < 8; ++e) {
            unsigned mb = ((e < 4 ? (mk8.x >> (8 * e)) : (mk8.y >> (8 * (e - 4)))) >> rr) & 1u;
            float v = lrelu(sv + Ds2[rr * 64 + jl0 + e]);
            v = mb ? v : NEGF;
            pv[e] = (short)f2bf(__expf(v - m) * z);
        }
        *(bf16x8*)&Ps[p * 8] = pv;
    }
    __syncthreads();

    const int w = t >> 6, lane = t & 63;
    const int ih = w & 1, ch = w >> 1;
    f32x4 acc[4] = {};
    const unsigned short* bbase0 = hT + (size_t)b * 128 * 1280
                                   + (size_t)(ch * 64 + (lane & 15)) * 1280 + j0 + (lane >> 4) * 8;
#pragma unroll
    for (int s = 0; s < 10; ++s) {
        bf16x8 af = *(const bf16x8*)&Ps[((ih * 10 + s) * 64 + lane) * 8];
        const int goff = (s >> 1) * 256 + (s & 1) * 32;    // r*256 + jl-offset for this k-step
#pragma unroll
        for (int ct = 0; ct < 4; ++ct) {
            bf16x8 bfv = *(const bf16x8*)(bbase0 + (size_t)ct * 16 * 1280 + goff);
            acc[ct] = __builtin_amdgcn_mfma_f32_16x16x32_bf16(af, bfv, acc[ct], 0, 0, 0);
        }
    }
    float* op = aggP + (size_t)js * 1048576;   // 8192*128
    const int irow = ib + ih * 16 + (lane >> 4) * 4;
#pragma unroll
    for (int ct = 0; ct < 4; ++ct) {
        int c = ch * 64 + ct * 16 + (lane & 15);
#pragma unroll
        for (int reg = 0; reg < 4; ++reg)
            op[(size_t)(irow + reg) * 128 + c] = acc[ct][reg];
    }
}

// ---------------- pooling over summed partials ----------------
__global__ __launch_bounds__(128) void k_pool(const float* __restrict__ aggP,
                                              float* __restrict__ feats) {
    int b = blockIdx.x, c = threadIdx.x;
    float sm = 0.f, mx = -3.4e38f;
    for (int n = 0; n < NN; ++n) {
        size_t o = ((size_t)(b * NN + n)) * 128 + c;
        float v = aggP[o] + aggP[o + 1048576] + aggP[o + 2097152] + aggP[o + 3145728];
        sm += v; mx = fmaxf(mx, v);
    }
    feats[b * 256 + c] = sm * (1.f / NN);
    feats[b * 256 + 128 + c] = mx;
}

// ---------------- MLP layer 1 (k-split partials): part[ks,b,o] ----------------
__global__ __launch_bounds__(256) void k_mlp1(const float* __restrict__ x,
                                              const float* __restrict__ feats,
                                              const float* __restrict__ We1,
                                              float* __restrict__ part) {
    int ks = blockIdx.x;
    int b = blockIdx.y;
    int o = threadIdx.x;
    __shared__ float zs[320];
    for (int k = o; k < 320; k += 256) {
        int gk = ks * 320 + k;
        zs[k] = (gk < 1024) ? x[b * 1024 + gk] : feats[b * 256 + gk - 1024];
    }
    __syncthreads();
    float s = 0.f;
    for (int k = 0; k < 320; ++k) s += zs[k] * We1[(size_t)(ks * 320 + k) * 256 + o];
    part[(size_t)(ks * 32 + b) * 256 + o] = s;
}

// ---------------- MLP layers 2+3 ----------------
__global__ __launch_bounds__(256) void k_mlp23(const float* __restrict__ part,
                                               const float* __restrict__ be1,
                                               const float* __restrict__ We2,
                                               const float* __restrict__ be2,
                                               const float* __restrict__ We3,
                                               const float* __restrict__ be3,
                                               float* __restrict__ out) {
    int b = blockIdx.x, t = threadIdx.x;
    __shared__ float zs[256], z2s[32];
    float s = part[(size_t)(0 + b) * 256 + t] + part[(size_t)(32 + b) * 256 + t] +
              part[(size_t)(64 + b) * 256 + t] + part[(size_t)(96 + b) * 256 + t] + be1[t];
    zs[t] = lrelu(s);
    __syncthreads();
    if (t < 32) {
        float s2 = be2[t];
        for (int k = 0; k < 256; ++k) s2 += zs[k] * We2[k * 32 + t];
        z2s[t] = lrelu(s2);
    }
    __syncthreads();
    if (t == 0) {
        float s3 = be3[0];
#pragma unroll
        for (int k = 0; k < 32; ++k) s3 += z2s[k] * We3[k];
        out[b] = s3;
    }
}

// ---------------- workspace layout ----------------
constexpr size_t O_MASK = 0;                                   // 2 MB
constexpr size_t O_SRCP = 2097152;                             // 2 halves x 40960 floats
constexpr size_t O_DSTP = O_SRCP + 2ull * 40960 * 4;
constexpr size_t O_M    = O_DSTP + 2ull * 40960 * 4;
constexpr size_t O_Z    = O_M + 8192ull * 4;
constexpr size_t O_AGG  = O_Z + 8192ull * 4;                   // 4 x 8192 x 128 fp32 = 16.8 MB
constexpr size_t O_FEAT = O_AGG + 4ull * 1048576 * 4;
constexpr size_t O_PART = O_FEAT + 32ull * 256 * 4;
constexpr size_t O_HT   = O_PART + 128ull * 256 * 4;           // hT bf16: 10.5 MB
constexpr size_t O_WT1  = O_HT + 8192ull * 1280 * 2;           // 640x64 bf16
constexpr size_t O_WT2  = O_WT1 + 640ull * 64 * 2;             // 640x128 bf16
constexpr size_t O_WT3  = O_WT2 + 640ull * 128 * 2;            // 640x128 bf16

extern "C" void kernel_launch(void* const* d_in, const int* in_sizes, int n_in,
                              void* d_out, int out_size, void* d_ws, size_t ws_size,
                              hipStream_t stream) {
    const float* x       = (const float*)d_in[0];
    const float* y_atoms = (const float*)d_in[1];
    const int*   y_bonds = (const int*)d_in[2];
    const float* W1 = (const float*)d_in[3];
    const float* b1 = (const float*)d_in[4];
    const float* a1 = (const float*)d_in[5];
    const float* W2 = (const float*)d_in[6];
    const float* b2 = (const float*)d_in[7];
    const float* a2 = (const float*)d_in[8];
    const float* W3 = (const float*)d_in[9];
    const float* b3 = (const float*)d_in[10];
    const float* a3 = (const float*)d_in[11];
    const float* We1 = (const float*)d_in[12];
    const float* be1 = (const float*)d_in[13];
    const float* We2 = (const float*)d_in[14];
    const float* be2 = (const float*)d_in[15];
    const float* We3 = (const float*)d_in[16];
    const float* be3 = (const float*)d_in[17];
    float* out = (float*)d_out;

    char* ws = (char*)d_ws;
    unsigned char* maskp = (unsigned char*)(ws + O_MASK);
    float* srcp = (float*)(ws + O_SRCP);
    float* dstp = (float*)(ws + O_DSTP);
    float* marr = (float*)(ws + O_M);
    float* zinv = (float*)(ws + O_Z);
    float* aggP = (float*)(ws + O_AGG);
    float* feats = (float*)(ws + O_FEAT);
    float* part  = (float*)(ws + O_PART);
    unsigned short* hT  = (unsigned short*)(ws + O_HT);
    unsigned short* WT1 = (unsigned short*)(ws + O_WT1);
    unsigned short* WT2 = (unsigned short*)(ws + O_WT2);
    unsigned short* WT3 = (unsigned short*)(ws + O_WT3);

    dim3 blk(256);

    k_prepw<<<30, blk, 0, stream>>>(W1, W2, W3, WT1, WT2, WT3);

    // layer 1
    k_gemm_h<64, false, false><<<dim3(10, 128), blk, 0, stream>>>(
        y_atoms, nullptr, WT1, b1, a1, srcp, dstp, hT);
    k_stats<true><<<8192, blk, 0, stream>>>(y_bonds, srcp, dstp, maskp, marr, zinv);
    k_agg<<<dim3(4, 8, 32), blk, 0, stream>>>(hT, srcp, dstp, maskp, marr, zinv, aggP);

    // layer 2
    k_gemm_h<128, true, true><<<dim3(10, 128), blk, 0, stream>>>(
        nullptr, aggP, WT2, b2, a2, srcp, dstp, hT);
    k_stats<false><<<8192, blk, 0, stream>>>(y_bonds, srcp, dstp, maskp, marr, zinv);
    k_agg<<<dim3(4, 8, 32), blk, 0, stream>>>(hT, srcp, dstp, maskp, marr, zinv, aggP);

    // layer 3
    k_gemm_h<128, true, true><<<dim3(10, 128), blk, 0, stream>>>(
        nullptr, aggP, WT3, b3, a3, srcp, dstp, hT);
    k_stats<false><<<8192, blk, 0, stream>>>(y_bonds, srcp, dstp, maskp, marr, zinv);
    k_agg<<<dim3(4, 8, 32), blk, 0, stream>>>(hT, srcp, dstp, maskp, marr, zinv, aggP);

    // pooling + MLP
    k_pool<<<32, dim3(128), 0, stream>>>(aggP, feats);
    k_mlp1<<<dim3(4, 32), blk, 0, stream>>>(x, feats, We1, part);
    k_mlp23<<<32, blk, 0, stream>>>(part, be1, We2, be2, We3, be3, out);
}

// Round 5
// 304.042 us; speedup vs baseline: 2.3117x; 1.0902x over previous
//
#include <hip/hip_runtime.h>
#include <cstddef>

#define BB 32
#define NN 256
#define RR 5
#define NEGF (-9.0e15f)

typedef __attribute__((ext_vector_type(8))) short bf16x8;
typedef __attribute__((ext_vector_type(4))) float f32x4;

__device__ __forceinline__ float lrelu(float x) { return x >= 0.f ? x : 0.2f * x; }
// RNE float -> bf16
__device__ __forceinline__ unsigned short f2bf(float x) {
    unsigned u = __float_as_uint(x);
    u += 0x7FFFu + ((u >> 16) & 1u);
    return (unsigned short)(u >> 16);
}

// =======================================================================================
// k_prepw: one-time transpose W (K x 640 fp32) -> WT (640 x K bf16) for all 3 layers.
// =======================================================================================
__global__ __launch_bounds__(256) void k_prepw(const float* __restrict__ W1,
                                               const float* __restrict__ W2,
                                               const float* __restrict__ W3,
                                               unsigned short* __restrict__ WT1,
                                               unsigned short* __restrict__ WT2,
                                               unsigned short* __restrict__ WT3) {
    int blk = blockIdx.x;
    int layer = blk / 10, nt = blk % 10;
    const float* W;
    unsigned short* WT;
    int K;
    if (layer == 0)      { W = W1; WT = WT1; K = 64; }
    else if (layer == 1) { W = W2; WT = WT2; K = 128; }
    else                 { W = W3; WT = WT3; K = 128; }
    int n = nt * 64 + (threadIdx.x & 63);
    for (int kg = (int)(threadIdx.x >> 6); kg < K / 8; kg += 4) {
        bf16x8 v;
#pragma unroll
        for (int e = 0; e < 8; ++e) v[e] = (short)f2bf(W[(size_t)(kg * 8 + e) * 640 + n]);
        *(bf16x8*)&WT[(size_t)n * K + kg * 8] = v;
    }
}

// =======================================================================================
// gemm_h: h = A(8192 x K) @ W(K x 640) + bias, MFMA bf16 (fp32 accum), no LDS at all.
//  - A fragments from global fp32 (SUMPARTS: sum of 4 aggP partials + leaky)
//  - B fragments from pre-transposed bf16 WT[n][k]
// Emits src/dst partial dots and hTf in fragment-native layout:
//   hTf[((b*5 + r)*32 + joct)*1024 + c*8 + e]   (joct = j/8, e = j%8)
// Direct register->global stores: per (ct) a wave writes two dense 256 B segments.
// grid (10 n-tiles of 64, 128 m-tiles of 64), 256 threads = 4 waves.
// =======================================================================================
template <int K, bool LEAKY, bool SUMPARTS>
__global__ __launch_bounds__(256) void k_gemm_h(const float* __restrict__ Adir,
                                                const float* __restrict__ Aparts,
                                                const unsigned short* __restrict__ WTg,
                                                const float* __restrict__ bias,
                                                const float* __restrict__ avec,
                                                float* __restrict__ srcp,
                                                float* __restrict__ dstp,
                                                unsigned short* __restrict__ hTf) {
    const int t = threadIdx.x;
    const int n0 = blockIdx.x * 64, m0 = blockIdx.y * 64;
    const int w = t >> 6, lane = t & 63;
    const int colg = lane & 15, rquad = lane >> 4;
    const int m = m0 + w * 16 + colg;        // A row this lane reads
    const int koff = rquad * 8;

    f32x4 acc[4] = {};
#pragma unroll
    for (int kk = 0; kk < K; kk += 32) {
        float av[8];
        size_t off = (size_t)m * K + kk + koff;
        if (SUMPARTS) {
            float4 q0 = *(const float4*)&Aparts[off];
            float4 q1 = *(const float4*)&Aparts[off + 4];
            float4 r0 = *(const float4*)&Aparts[off + 1048576];
            float4 r1 = *(const float4*)&Aparts[off + 1048576 + 4];
            float4 s0 = *(const float4*)&Aparts[off + 2097152];
            float4 s1 = *(const float4*)&Aparts[off + 2097152 + 4];
            float4 u0 = *(const float4*)&Aparts[off + 3145728];
            float4 u1 = *(const float4*)&Aparts[off + 3145728 + 4];
            av[0] = q0.x + r0.x + s0.x + u0.x; av[1] = q0.y + r0.y + s0.y + u0.y;
            av[2] = q0.z + r0.z + s0.z + u0.z; av[3] = q0.w + r0.w + s0.w + u0.w;
            av[4] = q1.x + r1.x + s1.x + u1.x; av[5] = q1.y + r1.y + s1.y + u1.y;
            av[6] = q1.z + r1.z + s1.z + u1.z; av[7] = q1.w + r1.w + s1.w + u1.w;
        } else {
            float4 q0 = *(const float4*)&Adir[off];
            float4 q1 = *(const float4*)&Adir[off + 4];
            av[0] = q0.x; av[1] = q0.y; av[2] = q0.z; av[3] = q0.w;
            av[4] = q1.x; av[5] = q1.y; av[6] = q1.z; av[7] = q1.w;
        }
        bf16x8 af;
#pragma unroll
        for (int e = 0; e < 8; ++e) {
            float v = av[e];
            if (LEAKY) v = lrelu(v);
            af[e] = (short)f2bf(v);
        }
#pragma unroll
        for (int ct = 0; ct < 4; ++ct) {
            bf16x8 bfv = *(const bf16x8*)&WTg[(size_t)(n0 + ct * 16 + colg) * K + kk + koff];
            acc[ct] = __builtin_amdgcn_mfma_f32_16x16x32_bf16(af, bfv, acc[ct], 0, 0, 0);
        }
    }

    // ---- epilogue: bias, src/dst partial dots (shfl-reduce over colg), hTf stores ----
    const int r = n0 >> 7, chalf = n0 & 127;
    const int b = m0 >> 8, jb = m0 & 255;
    float val[4][4];
    float ssum[4] = {0.f, 0.f, 0.f, 0.f}, dsum[4] = {0.f, 0.f, 0.f, 0.f};
#pragma unroll
    for (int ct = 0; ct < 4; ++ct) {
        int cg = chalf + ct * 16 + colg;
        float bv = bias[n0 + ct * 16 + colg];
        float asr = avec[r * 256 + cg];
        float ads = avec[r * 256 + 128 + cg];
#pragma unroll
        for (int reg = 0; reg < 4; ++reg) {
            float v = acc[ct][reg] + bv;
            val[ct][reg] = v;
            ssum[reg] += v * asr;
            dsum[reg] += v * ads;
        }
    }
#pragma unroll
    for (int mk = 1; mk < 16; mk <<= 1)
#pragma unroll
        for (int reg = 0; reg < 4; ++reg) {
            ssum[reg] += __shfl_xor(ssum[reg], mk);
            dsum[reg] += __shfl_xor(dsum[reg], mk);
        }
    if (colg == 0) {
        int half = (n0 >> 6) & 1;
#pragma unroll
        for (int reg = 0; reg < 4; ++reg) {
            int row = m0 + w * 16 + rquad * 4 + reg;
            srcp[half * 40960 + row * 5 + r] = ssum[reg];
            dstp[half * 40960 + row * 5 + r] = dsum[reg];
        }
    }
    // hTf direct stores: reg-quad = 4 consecutive j (8 B contiguous)
    {
        const int joct = (jb >> 3) + w * 2 + (rquad >> 1);
        const size_t tile = (size_t)((b * 5 + r) * 32 + joct) * 1024;
        const int sub = (rquad & 1) * 4;
#pragma unroll
        for (int ct = 0; ct < 4; ++ct) {
            int c = chalf + ct * 16 + colg;
            uint2 pk;
            pk.x = (unsigned)f2bf(val[ct][0]) | ((unsigned)f2bf(val[ct][1]) << 16);
            pk.y = (unsigned)f2bf(val[ct][2]) | ((unsigned)f2bf(val[ct][3]) << 16);
            *(uint2*)&hTf[tile + (size_t)c * 8 + sub] = pk;
        }
    }
}

// =======================================================================================
// softmax stats per (b,i). PACK variant reads y_bonds directly and emits maskp.
// =======================================================================================
template <bool PACK>
__global__ __launch_bounds__(256) void k_stats(const int* __restrict__ bonds,
                                               const float* __restrict__ srcp,
                                               const float* __restrict__ dstp,
                                               unsigned char* __restrict__ maskp,
                                               float* __restrict__ m_arr,
                                               float* __restrict__ zinv) {
    int row = blockIdx.x;                            // b*N + i
    int t = threadIdx.x;                             // j
    int b = row >> 8;
    float sv[5];
#pragma unroll
    for (int r = 0; r < 5; ++r)
        sv[r] = srcp[(size_t)row * 5 + r] + srcp[40960 + (size_t)row * 5 + r];

    const float* dp0 = dstp + ((size_t)(b << 8) + t) * 5;
    const float* dp1 = dp0 + 40960;
    unsigned mk;
    if (PACK) {
        const int* p = bonds + (((size_t)row << 8) + t) * 5;
        mk = 0;
#pragma unroll
        for (int r = 0; r < 5; ++r) mk |= (p[r] == 1) ? (1u << r) : 0u;
        maskp[((size_t)row << 8) + t] = (unsigned char)mk;
    } else {
        mk = maskp[((size_t)row << 8) + t];
    }
    float v[5];
#pragma unroll
    for (int r = 0; r < 5; ++r) {
        float xx = lrelu(sv[r] + dp0[r] + dp1[r]);
        v[r] = ((mk >> r) & 1) ? xx : NEGF;
    }
    float lmax = v[0];
#pragma unroll
    for (int r = 1; r < 5; ++r) lmax = fmaxf(lmax, v[r]);

    __shared__ float red[4], red2[4];
#pragma unroll
    for (int o = 32; o > 0; o >>= 1) lmax = fmaxf(lmax, __shfl_down(lmax, o));
    if ((t & 63) == 0) red[t >> 6] = lmax;
    __syncthreads();
    float m = fmaxf(fmaxf(red[0], red[1]), fmaxf(red[2], red[3]));

    float lsum = 0.f;
#pragma unroll
    for (int r = 0; r < 5; ++r) lsum += __expf(v[r] - m);
#pragma unroll
    for (int o = 32; o > 0; o >>= 1) lsum += __shfl_down(lsum, o);
    if ((t & 63) == 0) red2[t >> 6] = lsum;
    __syncthreads();
    if (t == 0) {
        float Z = red2[0] + red2[1] + red2[2] + red2[3];
        m_arr[row] = m;
        zinv[row] = 1.0f / Z;
    }
}

// =======================================================================================
// MFMA aggregation -> j-split partials aggP[js][row][c] (no atomics).
// 512 threads = 8 waves; wave w: i-quarter ihq = w&3, c-half ch = w>>2.
// Ps fragment-major: chunk p = bk*64 + lane, bk = ihq*10 + s.
// B from hTf tiles: dense 256 B segments.
// grid (4 j-splits of 64, 4 i-tiles of 64, 32 b).
// =======================================================================================
__global__ __launch_bounds__(512) void k_agg(const unsigned short* __restrict__ hTf,
                                             const float* __restrict__ srcp,
                                             const float* __restrict__ dstp,
                                             const unsigned char* __restrict__ maskp,
                                             const float* __restrict__ m_arr,
                                             const float* __restrict__ zinv,
                                             float* __restrict__ aggP) {
    __shared__ unsigned short Ps[20480];          // 40 bk x 64 chunks x 8 bf16 = 40 KB
    __shared__ float Ss[320], Ds2[320], Ms[64], Zs[64];
    const int t = threadIdx.x;
    const int js = blockIdx.x, itile = blockIdx.y, b = blockIdx.z;
    const int i0 = itile * 64, j0 = js * 64;
    const int ib = b * 256 + i0;

    if (t < 320) Ss[t] = srcp[(size_t)ib * 5 + t] + srcp[40960 + (size_t)ib * 5 + t];
    if (t >= 320 && t < 384) { int q = t - 320; Ms[q] = m_arr[ib + q]; Zs[q] = zinv[ib + q]; }
    {
        int idx = t & 511;
        if (idx < 320) {
            int jl = idx & 63, rr = idx >> 6;
            size_t o = (size_t)(b * 256 + j0 + jl) * 5 + rr;
            Ds2[idx] = dstp[o] + dstp[40960 + o];     // Ds2[r*64 + jl]
        }
    }
    __syncthreads();

    // P generation: 2560 chunks of 8, 5 per thread; one b128 LDS write per chunk
#pragma unroll
    for (int it = 0; it < 5; ++it) {
        int p = it * 512 + t;
        int lane8 = p & 63, bk = p >> 6;
        int colg8 = lane8 & 15, kq = lane8 >> 4;
        int ihq = bk / 10;
        int s = bk - ihq * 10;
        int i = ihq * 16 + colg8;
        int k0 = s * 32 + kq * 8;
        int rr = k0 >> 6, jl0 = k0 & 63;
        uint2 mk8 = *(const uint2*)&maskp[((size_t)(ib + i) << 8) + j0 + jl0];
        float sv = Ss[i * 5 + rr];
        float m = Ms[i], z = Zs[i];
        bf16x8 pv;
#pragma unroll
        for (int e = 0; e < 8; ++e) {
            unsigned mb = ((e < 4 ? (mk8.x >> (8 * e)) : (mk8.y >> (8 * (e - 4)))) >> rr) & 1u;
            float v = lrelu(sv + Ds2[rr * 64 + jl0 + e]);
            v = mb ? v : NEGF;
            pv[e] = (short)f2bf(__expf(v - m) * z);
        }
        *(bf16x8*)&Ps[p * 8] = pv;
    }
    __syncthreads();

    const int w = t >> 6, lane = t & 63;
    const int ihq = w & 3, ch = w >> 2;
    const int colg = lane & 15, rquad = lane >> 4;
    f32x4 acc[4] = {};
    const size_t bbase = (size_t)(b * 5) * 32 * 1024;
#pragma unroll
    for (int s = 0; s < 10; ++s) {
        bf16x8 af = *(const bf16x8*)&Ps[((ihq * 10 + s) * 64 + lane) * 8];
        const int r = s >> 1;
        const int joct = (j0 >> 3) + (s & 1) * 4 + rquad;
        const size_t tbase = bbase + (size_t)(r * 32 + joct) * 1024;
#pragma unroll
        for (int ct = 0; ct < 4; ++ct) {
            int c = ch * 64 + ct * 16 + colg;
            bf16x8 bfv = *(const bf16x8*)&hTf[tbase + (size_t)c * 8];
            acc[ct] = __builtin_amdgcn_mfma_f32_16x16x32_bf16(af, bfv, acc[ct], 0, 0, 0);
        }
    }
    float* op = aggP + (size_t)js * 1048576;   // 8192*128
    const int irow = ib + ihq * 16 + rquad * 4;
#pragma unroll
    for (int ct = 0; ct < 4; ++ct) {
        int c = ch * 64 + ct * 16 + colg;
#pragma unroll
        for (int reg = 0; reg < 4; ++reg)
            op[(size_t)(irow + reg) * 128 + c] = acc[ct][reg];
    }
}

// ---------------- pooling over summed partials ----------------
__global__ __launch_bounds__(128) void k_pool(const float* __restrict__ aggP,
                                              float* __restrict__ feats) {
    int b = blockIdx.x, c = threadIdx.x;
    float sm = 0.f, mx = -3.4e38f;
    for (int n = 0; n < NN; ++n) {
        size_t o = ((size_t)(b * NN + n)) * 128 + c;
        float v = aggP[o] + aggP[o + 1048576] + aggP[o + 2097152] + aggP[o + 3145728];
        sm += v; mx = fmaxf(mx, v);
    }
    feats[b * 256 + c] = sm * (1.f / NN);
    feats[b * 256 + 128 + c] = mx;
}

// ---------------- MLP layer 1 (k-split partials): part[ks,b,o] ----------------
__global__ __launch_bounds__(256) void k_mlp1(const float* __restrict__ x,
                                              const float* __restrict__ feats,
                                              const float* __restrict__ We1,
                                              float* __restrict__ part) {
    int ks = blockIdx.x;
    int b = blockIdx.y;
    int o = threadIdx.x;
    __shared__ float zs[320];
    for (int k = o; k < 320; k += 256) {
        int gk = ks * 320 + k;
        zs[k] = (gk < 1024) ? x[b * 1024 + gk] : feats[b * 256 + gk - 1024];
    }
    __syncthreads();
    float s = 0.f;
    for (int k = 0; k < 320; ++k) s += zs[k] * We1[(size_t)(ks * 320 + k) * 256 + o];
    part[(size_t)(ks * 32 + b) * 256 + o] = s;
}

// ---------------- MLP layers 2+3 ----------------
__global__ __launch_bounds__(256) void k_mlp23(const float* __restrict__ part,
                                               const float* __restrict__ be1,
                                               const float* __restrict__ We2,
                                               const float* __restrict__ be2,
                                               const float* __restrict__ We3,
                                               const float* __restrict__ be3,
                                               float* __restrict__ out) {
    int b = blockIdx.x, t = threadIdx.x;
    __shared__ float zs[256], z2s[32];
    float s = part[(size_t)(0 + b) * 256 + t] + part[(size_t)(32 + b) * 256 + t] +
              part[(size_t)(64 + b) * 256 + t] + part[(size_t)(96 + b) * 256 + t] + be1[t];
    zs[t] = lrelu(s);
    __syncthreads();
    if (t < 32) {
        float s2 = be2[t];
        for (int k = 0; k < 256; ++k) s2 += zs[k] * We2[k * 32 + t];
        z2s[t] = lrelu(s2);
    }
    __syncthreads();
    if (t == 0) {
        float s3 = be3[0];
#pragma unroll
        for (int k = 0; k < 32; ++k) s3 += z2s[k] * We3[k];
        out[b] = s3;
    }
}

// ---------------- workspace layout ----------------
constexpr size_t O_MASK = 0;                                   // 2 MB
constexpr size_t O_SRCP = 2097152;                             // 2 halves x 40960 floats
constexpr size_t O_DSTP = O_SRCP + 2ull * 40960 * 4;
constexpr size_t O_M    = O_DSTP + 2ull * 40960 * 4;
constexpr size_t O_Z    = O_M + 8192ull * 4;
constexpr size_t O_AGG  = O_Z + 8192ull * 4;                   // 4 x 8192 x 128 fp32 = 16.8 MB
constexpr size_t O_FEAT = O_AGG + 4ull * 1048576 * 4;
constexpr size_t O_PART = O_FEAT + 32ull * 256 * 4;
constexpr size_t O_HT   = O_PART + 128ull * 256 * 4;           // hTf bf16: 10.5 MB
constexpr size_t O_WT1  = O_HT + 5242880ull * 2;               // 640x64 bf16
constexpr size_t O_WT2  = O_WT1 + 640ull * 64 * 2;             // 640x128 bf16
constexpr size_t O_WT3  = O_WT2 + 640ull * 128 * 2;            // 640x128 bf16

extern "C" void kernel_launch(void* const* d_in, const int* in_sizes, int n_in,
                              void* d_out, int out_size, void* d_ws, size_t ws_size,
                              hipStream_t stream) {
    const float* x       = (const float*)d_in[0];
    const float* y_atoms = (const float*)d_in[1];
    const int*   y_bonds = (const int*)d_in[2];
    const float* W1 = (const float*)d_in[3];
    const float* b1 = (const float*)d_in[4];
    const float* a1 = (const float*)d_in[5];
    const float* W2 = (const float*)d_in[6];
    const float* b2 = (const float*)d_in[7];
    const float* a2 = (const float*)d_in[8];
    const float* W3 = (const float*)d_in[9];
    const float* b3 = (const float*)d_in[10];
    const float* a3 = (const float*)d_in[11];
    const float* We1 = (const float*)d_in[12];
    const float* be1 = (const float*)d_in[13];
    const float* We2 = (const float*)d_in[14];
    const float* be2 = (const float*)d_in[15];
    const float* We3 = (const float*)d_in[16];
    const float* be3 = (const float*)d_in[17];
    float* out = (float*)d_out;

    char* ws = (char*)d_ws;
    unsigned char* maskp = (unsigned char*)(ws + O_MASK);
    float* srcp = (float*)(ws + O_SRCP);
    float* dstp = (float*)(ws + O_DSTP);
    float* marr = (float*)(ws + O_M);
    float* zinv = (float*)(ws + O_Z);
    float* aggP = (float*)(ws + O_AGG);
    float* feats = (float*)(ws + O_FEAT);
    float* part  = (float*)(ws + O_PART);
    unsigned short* hTf = (unsigned short*)(ws + O_HT);
    unsigned short* WT1 = (unsigned short*)(ws + O_WT1);
    unsigned short* WT2 = (unsigned short*)(ws + O_WT2);
    unsigned short* WT3 = (unsigned short*)(ws + O_WT3);

    dim3 blk(256);

    k_prepw<<<30, blk, 0, stream>>>(W1, W2, W3, WT1, WT2, WT3);

    // layer 1
    k_gemm_h<64, false, false><<<dim3(10, 128), blk, 0, stream>>>(
        y_atoms, nullptr, WT1, b1, a1, srcp, dstp, hTf);
    k_stats<true><<<8192, blk, 0, stream>>>(y_bonds, srcp, dstp, maskp, marr, zinv);
    k_agg<<<dim3(4, 4, 32), dim3(512), 0, stream>>>(hTf, srcp, dstp, maskp, marr, zinv, aggP);

    // layer 2
    k_gemm_h<128, true, true><<<dim3(10, 128), blk, 0, stream>>>(
        nullptr, aggP, WT2, b2, a2, srcp, dstp, hTf);
    k_stats<false><<<8192, blk, 0, stream>>>(y_bonds, srcp, dstp, maskp, marr, zinv);
    k_agg<<<dim3(4, 4, 32), dim3(512), 0, stream>>>(hTf, srcp, dstp, maskp, marr, zinv, aggP);

    // layer 3
    k_gemm_h<128, true, true><<<dim3(10, 128), blk, 0, stream>>>(
        nullptr, aggP, WT3, b3, a3, srcp, dstp, hTf);
    k_stats<false><<<8192, blk, 0, stream>>>(y_bonds, srcp, dstp, maskp, marr, zinv);
    k_agg<<<dim3(4, 4, 32), dim3(512), 0, stream>>>(hTf, srcp, dstp, maskp, marr, zinv, aggP);

    // pooling + MLP
    k_pool<<<32, dim3(128), 0, stream>>>(aggP, feats);
    k_mlp1<<<dim3(4, 32), blk, 0, stream>>>(x, feats, We1, part);
    k_mlp23<<<32, blk, 0, stream>>>(part, be1, We2, be2, We3, be3, out);
}

// Round 6
// 274.570 us; speedup vs baseline: 2.5598x; 1.1073x over previous
//
#include <hip/hip_runtime.h>
#include <cstddef>

#define BB 32
#define NN 256
#define RR 5

typedef __attribute__((ext_vector_type(8))) short bf16x8;
typedef __attribute__((ext_vector_type(4))) float f32x4;

__device__ __forceinline__ float lrelu(float x) { return x >= 0.f ? x : 0.2f * x; }
// RNE float -> bf16
__device__ __forceinline__ unsigned short f2bf(float x) {
    unsigned u = __float_as_uint(x);
    u += 0x7FFFu + ((u >> 16) & 1u);
    return (unsigned short)(u >> 16);
}

// =======================================================================================
// k_prepw: one-time transpose W (K x 640 fp32) -> WT (640 x K bf16) for all 3 layers.
// =======================================================================================
__global__ __launch_bounds__(256) void k_prepw(const float* __restrict__ W1,
                                               const float* __restrict__ W2,
                                               const float* __restrict__ W3,
                                               unsigned short* __restrict__ WT1,
                                               unsigned short* __restrict__ WT2,
                                               unsigned short* __restrict__ WT3) {
    int blk = blockIdx.x;
    int layer = blk / 10, nt = blk % 10;
    const float* W;
    unsigned short* WT;
    int K;
    if (layer == 0)      { W = W1; WT = WT1; K = 64; }
    else if (layer == 1) { W = W2; WT = WT2; K = 128; }
    else                 { W = W3; WT = WT3; K = 128; }
    int n = nt * 64 + (threadIdx.x & 63);
    for (int kg = (int)(threadIdx.x >> 6); kg < K / 8; kg += 4) {
        bf16x8 v;
#pragma unroll
        for (int e = 0; e < 8; ++e) v[e] = (short)f2bf(W[(size_t)(kg * 8 + e) * 640 + n]);
        *(bf16x8*)&WT[(size_t)n * K + kg * 8] = v;
    }
}

// ---------------- pack y_bonds (B,N,N,5) int32 -> 5-bit mask per (b,i,j) ----------------
__global__ __launch_bounds__(256) void k_pack(const int* __restrict__ bonds,
                                              unsigned char* __restrict__ maskp) {
    int t = blockIdx.x * 256 + threadIdx.x;          // B*N*N threads
    const int* p = bonds + (size_t)t * 5;
    unsigned m = 0;
#pragma unroll
    for (int r = 0; r < 5; ++r) m |= (p[r] == 1) ? (1u << r) : 0u;
    maskp[t] = (unsigned char)m;
}

// =======================================================================================
// gemm_h: h = A(8192 x K) @ W(K x 640) + bias, MFMA bf16 (fp32 accum), no LDS staging.
//  - ABF16=false: A from fp32 (layer 1, y_atoms); ABF16=true: A from bf16 Abf (norm'd)
//  - B from pre-transposed bf16 WT[n][k]
// Emits src/dst partial dots (2 halves) and hTf fragment-native:
//   hTf[((b*5 + r)*32 + joct)*1024 + c*8 + e]   (joct = j/8, e = j%8)
// grid (10 n-tiles of 64, 128 m-tiles of 64), 256 threads = 4 waves.
// =======================================================================================
template <int K, bool ABF16>
__global__ __launch_bounds__(256) void k_gemm_h(const float* __restrict__ Af32,
                                                const unsigned short* __restrict__ Abf,
                                                const unsigned short* __restrict__ WTg,
                                                const float* __restrict__ bias,
                                                const float* __restrict__ avec,
                                                float* __restrict__ srcp,
                                                float* __restrict__ dstp,
                                                unsigned short* __restrict__ hTf) {
    const int t = threadIdx.x;
    const int n0 = blockIdx.x * 64, m0 = blockIdx.y * 64;
    const int w = t >> 6, lane = t & 63;
    const int colg = lane & 15, rquad = lane >> 4;
    const int m = m0 + w * 16 + colg;        // A row this lane reads
    const int koff = rquad * 8;

    f32x4 acc[4] = {};
#pragma unroll
    for (int kk = 0; kk < K; kk += 32) {
        bf16x8 af;
        if (ABF16) {
            af = *(const bf16x8*)&Abf[(size_t)m * K + kk + koff];
        } else {
            size_t off = (size_t)m * K + kk + koff;
            float4 q0 = *(const float4*)&Af32[off];
            float4 q1 = *(const float4*)&Af32[off + 4];
            af[0] = (short)f2bf(q0.x); af[1] = (short)f2bf(q0.y);
            af[2] = (short)f2bf(q0.z); af[3] = (short)f2bf(q0.w);
            af[4] = (short)f2bf(q1.x); af[5] = (short)f2bf(q1.y);
            af[6] = (short)f2bf(q1.z); af[7] = (short)f2bf(q1.w);
        }
#pragma unroll
        for (int ct = 0; ct < 4; ++ct) {
            bf16x8 bfv = *(const bf16x8*)&WTg[(size_t)(n0 + ct * 16 + colg) * K + kk + koff];
            acc[ct] = __builtin_amdgcn_mfma_f32_16x16x32_bf16(af, bfv, acc[ct], 0, 0, 0);
        }
    }

    // ---- epilogue: bias, src/dst partial dots (shfl-reduce over colg), hTf stores ----
    const int r = n0 >> 7, chalf = n0 & 127;
    const int b = m0 >> 8, jb = m0 & 255;
    float val[4][4];
    float ssum[4] = {0.f, 0.f, 0.f, 0.f}, dsum[4] = {0.f, 0.f, 0.f, 0.f};
#pragma unroll
    for (int ct = 0; ct < 4; ++ct) {
        int cg = chalf + ct * 16 + colg;
        float bv = bias[n0 + ct * 16 + colg];
        float asr = avec[r * 256 + cg];
        float ads = avec[r * 256 + 128 + cg];
#pragma unroll
        for (int reg = 0; reg < 4; ++reg) {
            float v = acc[ct][reg] + bv;
            val[ct][reg] = v;
            ssum[reg] += v * asr;
            dsum[reg] += v * ads;
        }
    }
#pragma unroll
    for (int mk = 1; mk < 16; mk <<= 1)
#pragma unroll
        for (int reg = 0; reg < 4; ++reg) {
            ssum[reg] += __shfl_xor(ssum[reg], mk);
            dsum[reg] += __shfl_xor(dsum[reg], mk);
        }
    if (colg == 0) {
        int half = (n0 >> 6) & 1;
#pragma unroll
        for (int reg = 0; reg < 4; ++reg) {
            int row = m0 + w * 16 + rquad * 4 + reg;
            srcp[half * 40960 + row * 5 + r] = ssum[reg];
            dstp[half * 40960 + row * 5 + r] = dsum[reg];
        }
    }
    // hTf direct stores: reg-quad = 4 consecutive j (8 B contiguous)
    {
        const int joct = (jb >> 3) + w * 2 + (rquad >> 1);
        const size_t tile = (size_t)((b * 5 + r) * 32 + joct) * 1024;
        const int sub = (rquad & 1) * 4;
#pragma unroll
        for (int ct = 0; ct < 4; ++ct) {
            int c = chalf + ct * 16 + colg;
            uint2 pk;
            pk.x = (unsigned)f2bf(val[ct][0]) | ((unsigned)f2bf(val[ct][1]) << 16);
            pk.y = (unsigned)f2bf(val[ct][2]) | ((unsigned)f2bf(val[ct][3]) << 16);
            *(uint2*)&hTf[tile + (size_t)c * 8 + sub] = pk;
        }
    }
}

// =======================================================================================
// MFMA aggregation, UNNORMALIZED softmax: e = mask ? exp(lrelu(src+dst)) : 0 (bf16).
// Accumulates Zrow = sum_j,r e (fp32, from the same bf16 values the MFMA sums) in LDS.
// Writes j-split partials aggP[js][row][c] and Zpart[js][row]. No atomics on global.
// 512 threads = 8 waves; wave w: i-quarter ihq = w&3, c-half ch = w>>2.
// grid (4 j-splits of 64, 4 i-tiles of 64, 32 b).
// =======================================================================================
__global__ __launch_bounds__(512) void k_agg(const unsigned short* __restrict__ hTf,
                                             const float* __restrict__ srcp,
                                             const float* __restrict__ dstp,
                                             const unsigned char* __restrict__ maskp,
                                             float* __restrict__ aggP,
                                             float* __restrict__ Zpart) {
    __shared__ unsigned short Ps[20480];          // 40 bk x 64 chunks x 8 bf16 = 40 KB
    __shared__ float Ss[320], Ds2[320], Zrow[64];
    const int t = threadIdx.x;
    const int js = blockIdx.x, itile = blockIdx.y, b = blockIdx.z;
    const int i0 = itile * 64, j0 = js * 64;
    const int ib = b * 256 + i0;

    if (t < 320) Ss[t] = srcp[(size_t)ib * 5 + t] + srcp[40960 + (size_t)ib * 5 + t];
    if (t >= 320 && t < 384) Zrow[t - 320] = 0.f;
    if (t < 320) {
        int jl = t & 63, rr = t >> 6;
        size_t o = (size_t)(b * 256 + j0 + jl) * 5 + rr;
        Ds2[t] = dstp[o] + dstp[40960 + o];       // Ds2[r*64 + jl]
    }
    __syncthreads();

    // P generation: 2560 chunks of 8, 5 per thread; one b128 LDS write per chunk
#pragma unroll
    for (int it = 0; it < 5; ++it) {
        int p = it * 512 + t;
        int lane8 = p & 63, bk = p >> 6;
        int colg8 = lane8 & 15, kq = lane8 >> 4;
        int ihq = bk / 10;
        int s = bk - ihq * 10;
        int i = ihq * 16 + colg8;
        int k0 = s * 32 + kq * 8;
        int rr = k0 >> 6, jl0 = k0 & 63;
        uint2 mk8 = *(const uint2*)&maskp[((size_t)(ib + i) << 8) + j0 + jl0];
        float sv = Ss[i * 5 + rr];
        float esum = 0.f;
        bf16x8 pv;
#pragma unroll
        for (int e = 0; e < 8; ++e) {
            unsigned mb = ((e < 4 ? (mk8.x >> (8 * e)) : (mk8.y >> (8 * (e - 4)))) >> rr) & 1u;
            float v = lrelu(sv + Ds2[rr * 64 + jl0 + e]);
            float ev = mb ? __expf(v) : 0.f;
            unsigned short q = f2bf(ev);
            pv[e] = (short)q;
            esum += __uint_as_float((unsigned)q << 16);
        }
        *(bf16x8*)&Ps[p * 8] = pv;
        atomicAdd(&Zrow[i], esum);
    }
    __syncthreads();
    if (t < 64) Zpart[(size_t)js * 8192 + ib + t] = Zrow[t];

    const int w = t >> 6, lane = t & 63;
    const int ihq = w & 3, ch = w >> 2;
    const int colg = lane & 15, rquad = lane >> 4;
    f32x4 acc[4] = {};
    const size_t bbase = (size_t)(b * 5) * 32 * 1024;
#pragma unroll
    for (int s = 0; s < 10; ++s) {
        bf16x8 af = *(const bf16x8*)&Ps[((ihq * 10 + s) * 64 + lane) * 8];
        const int r = s >> 1;
        const int joct = (j0 >> 3) + (s & 1) * 4 + rquad;
        const size_t tbase = bbase + (size_t)(r * 32 + joct) * 1024;
#pragma unroll
        for (int ct = 0; ct < 4; ++ct) {
            int c = ch * 64 + ct * 16 + colg;
            bf16x8 bfv = *(const bf16x8*)&hTf[tbase + (size_t)c * 8];
            acc[ct] = __builtin_amdgcn_mfma_f32_16x16x32_bf16(af, bfv, acc[ct], 0, 0, 0);
        }
    }
    float* op = aggP + (size_t)js * 1048576;   // 8192*128
    const int irow = ib + ihq * 16 + rquad * 4;
#pragma unroll
    for (int ct = 0; ct < 4; ++ct) {
        int c = ch * 64 + ct * 16 + colg;
#pragma unroll
        for (int reg = 0; reg < 4; ++reg)
            op[(size_t)(irow + reg) * 128 + c] = acc[ct][reg];
    }
}

// =======================================================================================
// k_norm: Abf[row][c] = bf16( lrelu( (sum_js aggP) / (sum_js Zpart) ) )  — 2 MB out.
// 512 blocks x 256 threads x 8 c each.
// =======================================================================================
__global__ __launch_bounds__(256) void k_norm(const float* __restrict__ aggP,
                                              const float* __restrict__ Zpart,
                                              unsigned short* __restrict__ Abf) {
    int idx8 = blockIdx.x * 256 + threadIdx.x;
    int row = idx8 >> 4, c0 = (idx8 & 15) * 8;
    float Z = Zpart[row] + Zpart[8192 + row] + Zpart[16384 + row] + Zpart[24576 + row];
    float zi = 1.f / Z;
    size_t o = (size_t)row * 128 + c0;
    float v[8];
#pragma unroll
    for (int h = 0; h < 2; ++h) {
        float4 s0 = *(const float4*)&aggP[o + h * 4];
        float4 s1 = *(const float4*)&aggP[o + h * 4 + 1048576];
        float4 s2 = *(const float4*)&aggP[o + h * 4 + 2097152];
        float4 s3 = *(const float4*)&aggP[o + h * 4 + 3145728];
        v[h * 4 + 0] = s0.x + s1.x + s2.x + s3.x;
        v[h * 4 + 1] = s0.y + s1.y + s2.y + s3.y;
        v[h * 4 + 2] = s0.z + s1.z + s2.z + s3.z;
        v[h * 4 + 3] = s0.w + s1.w + s2.w + s3.w;
    }
    bf16x8 ob;
#pragma unroll
    for (int e = 0; e < 8; ++e) ob[e] = (short)f2bf(lrelu(v[e] * zi));
    *(bf16x8*)&Abf[o] = ob;
}

// =======================================================================================
// MLP layer 1 (k-split partials). Block ks==3 computes the mean/max pooling inline
// (h3 = (sum aggP)/Z, NO leaky after layer 3 — matches reference).
// =======================================================================================
__global__ __launch_bounds__(256) void k_mlp1(const float* __restrict__ x,
                                              const float* __restrict__ aggP,
                                              const float* __restrict__ Zpart,
                                              const float* __restrict__ We1,
                                              float* __restrict__ part) {
    int ks = blockIdx.x, b = blockIdx.y, t = threadIdx.x;
    __shared__ float zs[320];
    __shared__ float Zi[256], S2[2][128], M2[2][128];

    if (ks == 3) {
        int rowg = b * 256 + t;
        Zi[t] = 1.f / (Zpart[rowg] + Zpart[8192 + rowg] + Zpart[16384 + rowg] + Zpart[24576 + rowg]);
        __syncthreads();
        int c = t & 127, half = t >> 7;
        float sm = 0.f, mx = -3.4e38f;
        for (int n = half * 128; n < half * 128 + 128; ++n) {
            size_t o = (size_t)(b * 256 + n) * 128 + c;
            float v = (aggP[o] + aggP[o + 1048576] + aggP[o + 2097152] + aggP[o + 3145728]) * Zi[n];
            sm += v; mx = fmaxf(mx, v);
        }
        S2[half][c] = sm; M2[half][c] = mx;
        __syncthreads();
        for (int k = t; k < 320; k += 256) {
            int gk = 960 + k;
            float v;
            if (gk < 1024) v = x[b * 1024 + gk];
            else {
                int f = gk - 1024;
                v = (f < 128) ? (S2[0][f] + S2[1][f]) * (1.f / 256.f)
                              : fmaxf(M2[0][f - 128], M2[1][f - 128]);
            }
            zs[k] = v;
        }
    } else {
        for (int k = t; k < 320; k += 256) zs[k] = x[b * 1024 + ks * 320 + k];
    }
    __syncthreads();
    float s = 0.f;
    for (int k = 0; k < 320; ++k) s += zs[k] * We1[(size_t)(ks * 320 + k) * 256 + t];
    part[(size_t)(ks * 32 + b) * 256 + t] = s;
}

// ---------------- MLP layers 2+3 ----------------
__global__ __launch_bounds__(256) void k_mlp23(const float* __restrict__ part,
                                               const float* __restrict__ be1,
                                               const float* __restrict__ We2,
                                               const float* __restrict__ be2,
                                               const float* __restrict__ We3,
                                               const float* __restrict__ be3,
                                               float* __restrict__ out) {
    int b = blockIdx.x, t = threadIdx.x;
    __shared__ float zs[256], z2s[32];
    float s = part[(size_t)(0 + b) * 256 + t] + part[(size_t)(32 + b) * 256 + t] +
              part[(size_t)(64 + b) * 256 + t] + part[(size_t)(96 + b) * 256 + t] + be1[t];
    zs[t] = lrelu(s);
    __syncthreads();
    if (t < 32) {
        float s2 = be2[t];
        for (int k = 0; k < 256; ++k) s2 += zs[k] * We2[k * 32 + t];
        z2s[t] = lrelu(s2);
    }
    __syncthreads();
    if (t == 0) {
        float s3 = be3[0];
#pragma unroll
        for (int k = 0; k < 32; ++k) s3 += z2s[k] * We3[k];
        out[b] = s3;
    }
}

// ---------------- workspace layout ----------------
constexpr size_t O_MASK = 0;                                   // 2 MB
constexpr size_t O_SRCP = 2097152;                             // 2 halves x 40960 floats
constexpr size_t O_DSTP = O_SRCP + 2ull * 40960 * 4;
constexpr size_t O_ZP   = O_DSTP + 2ull * 40960 * 4;           // 4 x 8192 floats
constexpr size_t O_AGG  = O_ZP + 4ull * 8192 * 4;              // 4 x 8192 x 128 fp32 = 16.8 MB
constexpr size_t O_ABF  = O_AGG + 4ull * 1048576 * 4;          // 8192x128 bf16 = 2 MB
constexpr size_t O_PART = O_ABF + 1048576ull * 2;
constexpr size_t O_HT   = O_PART + 128ull * 256 * 4;           // hTf bf16: 10.5 MB
constexpr size_t O_WT1  = O_HT + 5242880ull * 2;
constexpr size_t O_WT2  = O_WT1 + 640ull * 64 * 2;
constexpr size_t O_WT3  = O_WT2 + 640ull * 128 * 2;

extern "C" void kernel_launch(void* const* d_in, const int* in_sizes, int n_in,
                              void* d_out, int out_size, void* d_ws, size_t ws_size,
                              hipStream_t stream) {
    const float* x       = (const float*)d_in[0];
    const float* y_atoms = (const float*)d_in[1];
    const int*   y_bonds = (const int*)d_in[2];
    const float* W1 = (const float*)d_in[3];
    const float* b1 = (const float*)d_in[4];
    const float* a1 = (const float*)d_in[5];
    const float* W2 = (const float*)d_in[6];
    const float* b2 = (const float*)d_in[7];
    const float* a2 = (const float*)d_in[8];
    const float* W3 = (const float*)d_in[9];
    const float* b3 = (const float*)d_in[10];
    const float* a3 = (const float*)d_in[11];
    const float* We1 = (const float*)d_in[12];
    const float* be1 = (const float*)d_in[13];
    const float* We2 = (const float*)d_in[14];
    const float* be2 = (const float*)d_in[15];
    const float* We3 = (const float*)d_in[16];
    const float* be3 = (const float*)d_in[17];
    float* out = (float*)d_out;

    char* ws = (char*)d_ws;
    unsigned char* maskp = (unsigned char*)(ws + O_MASK);
    float* srcp = (float*)(ws + O_SRCP);
    float* dstp = (float*)(ws + O_DSTP);
    float* Zpart = (float*)(ws + O_ZP);
    float* aggP = (float*)(ws + O_AGG);
    unsigned short* Abf = (unsigned short*)(ws + O_ABF);
    float* part  = (float*)(ws + O_PART);
    unsigned short* hTf = (unsigned short*)(ws + O_HT);
    unsigned short* WT1 = (unsigned short*)(ws + O_WT1);
    unsigned short* WT2 = (unsigned short*)(ws + O_WT2);
    unsigned short* WT3 = (unsigned short*)(ws + O_WT3);

    dim3 blk(256);

    k_prepw<<<30, blk, 0, stream>>>(W1, W2, W3, WT1, WT2, WT3);
    k_pack<<<8192, blk, 0, stream>>>(y_bonds, maskp);

    // layer 1
    k_gemm_h<64, false><<<dim3(10, 128), blk, 0, stream>>>(
        y_atoms, nullptr, WT1, b1, a1, srcp, dstp, hTf);
    k_agg<<<dim3(4, 4, 32), dim3(512), 0, stream>>>(hTf, srcp, dstp, maskp, aggP, Zpart);

    // layer 2
    k_norm<<<512, blk, 0, stream>>>(aggP, Zpart, Abf);
    k_gemm_h<128, true><<<dim3(10, 128), blk, 0, stream>>>(
        nullptr, Abf, WT2, b2, a2, srcp, dstp, hTf);
    k_agg<<<dim3(4, 4, 32), dim3(512), 0, stream>>>(hTf, srcp, dstp, maskp, aggP, Zpart);

    // layer 3
    k_norm<<<512, blk, 0, stream>>>(aggP, Zpart, Abf);
    k_gemm_h<128, true><<<dim3(10, 128), blk, 0, stream>>>(
        nullptr, Abf, WT3, b3, a3, srcp, dstp, hTf);
    k_agg<<<dim3(4, 4, 32), dim3(512), 0, stream>>>(hTf, srcp, dstp, maskp, aggP, Zpart);

    // pooling (inline in ks==3) + MLP
    k_mlp1<<<dim3(4, 32), blk, 0, stream>>>(x, aggP, Zpart, We1, part);
    k_mlp23<<<32, blk, 0, stream>>>(part, be1, We2, be2, We3, be3, out);
}

// Round 7
// 237.412 us; speedup vs baseline: 2.9605x; 1.1565x over previous
//
#include <hip/hip_runtime.h>
#include <cstddef>

#define BB 32
#define NN 256
#define RR 5

typedef __attribute__((ext_vector_type(8))) short bf16x8;
typedef __attribute__((ext_vector_type(4))) float f32x4;

__device__ __forceinline__ float lrelu(float x) { return x >= 0.f ? x : 0.2f * x; }
// RNE float -> bf16
__device__ __forceinline__ unsigned short f2bf(float x) {
    unsigned u = __float_as_uint(x);
    u += 0x7FFFu + ((u >> 16) & 1u);
    return (unsigned short)(u >> 16);
}

// =======================================================================================
// k_prepw: one-time weight prep.
// blocks 0..29: transpose W (K x 640 fp32) -> WT (640 x K bf16) for the 3 GAT layers.
// blocks 30..61: transpose We1 (1280 x 256 fp32) -> We1T (256 x 1280 fp32).
// =======================================================================================
__global__ __launch_bounds__(256) void k_prepw(const float* __restrict__ W1,
                                               const float* __restrict__ W2,
                                               const float* __restrict__ W3,
                                               const float* __restrict__ We1,
                                               unsigned short* __restrict__ WT1,
                                               unsigned short* __restrict__ WT2,
                                               unsigned short* __restrict__ WT3,
                                               float* __restrict__ We1T) {
    __shared__ float Ls[40][256];
    int blk = blockIdx.x;
    int t = threadIdx.x;
    if (blk < 30) {
        int layer = blk / 10, nt = blk % 10;
        const float* W;
        unsigned short* WT;
        int K;
        if (layer == 0)      { W = W1; WT = WT1; K = 64; }
        else if (layer == 1) { W = W2; WT = WT2; K = 128; }
        else                 { W = W3; WT = WT3; K = 128; }
        int n = nt * 64 + (t & 63);
        for (int kg = (int)(t >> 6); kg < K / 8; kg += 4) {
            bf16x8 v;
#pragma unroll
            for (int e = 0; e < 8; ++e) v[e] = (short)f2bf(W[(size_t)(kg * 8 + e) * 640 + n]);
            *(bf16x8*)&WT[(size_t)n * K + kg * 8] = v;
        }
    } else {
        int bt = blk - 30;                         // k-range [bt*40, bt*40+40)
        for (int kk = 0; kk < 40; ++kk)
            Ls[kk][t] = We1[(size_t)(bt * 40 + kk) * 256 + t];
        __syncthreads();
#pragma unroll
        for (int q = 0; q < 10; ++q) {
            float4 v;
            v.x = Ls[q * 4 + 0][t]; v.y = Ls[q * 4 + 1][t];
            v.z = Ls[q * 4 + 2][t]; v.w = Ls[q * 4 + 3][t];
            *(float4*)&We1T[(size_t)t * 1280 + bt * 40 + q * 4] = v;
        }
    }
}

// ---------------- pack y_bonds (B,N,N,5) int32 -> 5-bit mask per (b,i,j) ----------------
__global__ __launch_bounds__(256) void k_pack(const int* __restrict__ bonds,
                                              unsigned char* __restrict__ maskp) {
    int t = blockIdx.x * 256 + threadIdx.x;          // B*N*N threads
    const int* p = bonds + (size_t)t * 5;
    unsigned m = 0;
#pragma unroll
    for (int r = 0; r < 5; ++r) m |= (p[r] == 1) ? (1u << r) : 0u;
    maskp[t] = (unsigned char)m;
}

// =======================================================================================
// gemm_h: h = A(8192 x K) @ W(K x 640) + bias, MFMA bf16 (fp32 accum), no LDS staging.
// =======================================================================================
template <int K, bool ABF16>
__global__ __launch_bounds__(256) void k_gemm_h(const float* __restrict__ Af32,
                                                const unsigned short* __restrict__ Abf,
                                                const unsigned short* __restrict__ WTg,
                                                const float* __restrict__ bias,
                                                const float* __restrict__ avec,
                                                float* __restrict__ srcp,
                                                float* __restrict__ dstp,
                                                unsigned short* __restrict__ hTf) {
    const int t = threadIdx.x;
    const int n0 = blockIdx.x * 64, m0 = blockIdx.y * 64;
    const int w = t >> 6, lane = t & 63;
    const int colg = lane & 15, rquad = lane >> 4;
    const int m = m0 + w * 16 + colg;        // A row this lane reads
    const int koff = rquad * 8;

    f32x4 acc[4] = {};
#pragma unroll
    for (int kk = 0; kk < K; kk += 32) {
        bf16x8 af;
        if (ABF16) {
            af = *(const bf16x8*)&Abf[(size_t)m * K + kk + koff];
        } else {
            size_t off = (size_t)m * K + kk + koff;
            float4 q0 = *(const float4*)&Af32[off];
            float4 q1 = *(const float4*)&Af32[off + 4];
            af[0] = (short)f2bf(q0.x); af[1] = (short)f2bf(q0.y);
            af[2] = (short)f2bf(q0.z); af[3] = (short)f2bf(q0.w);
            af[4] = (short)f2bf(q1.x); af[5] = (short)f2bf(q1.y);
            af[6] = (short)f2bf(q1.z); af[7] = (short)f2bf(q1.w);
        }
#pragma unroll
        for (int ct = 0; ct < 4; ++ct) {
            bf16x8 bfv = *(const bf16x8*)&WTg[(size_t)(n0 + ct * 16 + colg) * K + kk + koff];
            acc[ct] = __builtin_amdgcn_mfma_f32_16x16x32_bf16(af, bfv, acc[ct], 0, 0, 0);
        }
    }

    // ---- epilogue: bias, src/dst partial dots (shfl-reduce over colg), hTf stores ----
    const int r = n0 >> 7, chalf = n0 & 127;
    const int b = m0 >> 8, jb = m0 & 255;
    float val[4][4];
    float ssum[4] = {0.f, 0.f, 0.f, 0.f}, dsum[4] = {0.f, 0.f, 0.f, 0.f};
#pragma unroll
    for (int ct = 0; ct < 4; ++ct) {
        int cg = chalf + ct * 16 + colg;
        float bv = bias[n0 + ct * 16 + colg];
        float asr = avec[r * 256 + cg];
        float ads = avec[r * 256 + 128 + cg];
#pragma unroll
        for (int reg = 0; reg < 4; ++reg) {
            float v = acc[ct][reg] + bv;
            val[ct][reg] = v;
            ssum[reg] += v * asr;
            dsum[reg] += v * ads;
        }
    }
#pragma unroll
    for (int mk = 1; mk < 16; mk <<= 1)
#pragma unroll
        for (int reg = 0; reg < 4; ++reg) {
            ssum[reg] += __shfl_xor(ssum[reg], mk);
            dsum[reg] += __shfl_xor(dsum[reg], mk);
        }
    if (colg == 0) {
        int half = (n0 >> 6) & 1;
#pragma unroll
        for (int reg = 0; reg < 4; ++reg) {
            int row = m0 + w * 16 + rquad * 4 + reg;
            srcp[half * 40960 + row * 5 + r] = ssum[reg];
            dstp[half * 40960 + row * 5 + r] = dsum[reg];
        }
    }
    // hTf direct stores: reg-quad = 4 consecutive j (8 B contiguous)
    {
        const int joct = (jb >> 3) + w * 2 + (rquad >> 1);
        const size_t tile = (size_t)((b * 5 + r) * 32 + joct) * 1024;
        const int sub = (rquad & 1) * 4;
#pragma unroll
        for (int ct = 0; ct < 4; ++ct) {
            int c = chalf + ct * 16 + colg;
            uint2 pk;
            pk.x = (unsigned)f2bf(val[ct][0]) | ((unsigned)f2bf(val[ct][1]) << 16);
            pk.y = (unsigned)f2bf(val[ct][2]) | ((unsigned)f2bf(val[ct][3]) << 16);
            *(uint2*)&hTf[tile + (size_t)c * 8 + sub] = pk;
        }
    }
}

// =======================================================================================
// MFMA aggregation, UNNORMALIZED softmax: e = mask ? exp(lrelu(src+dst)) : 0 (bf16).
// =======================================================================================
__global__ __launch_bounds__(512) void k_agg(const unsigned short* __restrict__ hTf,
                                             const float* __restrict__ srcp,
                                             const float* __restrict__ dstp,
                                             const unsigned char* __restrict__ maskp,
                                             float* __restrict__ aggP,
                                             float* __restrict__ Zpart) {
    __shared__ unsigned short Ps[20480];          // 40 bk x 64 chunks x 8 bf16 = 40 KB
    __shared__ float Ss[320], Ds2[320], Zrow[64];
    const int t = threadIdx.x;
    const int js = blockIdx.x, itile = blockIdx.y, b = blockIdx.z;
    const int i0 = itile * 64, j0 = js * 64;
    const int ib = b * 256 + i0;

    if (t < 320) Ss[t] = srcp[(size_t)ib * 5 + t] + srcp[40960 + (size_t)ib * 5 + t];
    if (t >= 320 && t < 384) Zrow[t - 320] = 0.f;
    if (t < 320) {
        int jl = t & 63, rr = t >> 6;
        size_t o = (size_t)(b * 256 + j0 + jl) * 5 + rr;
        Ds2[t] = dstp[o] + dstp[40960 + o];       // Ds2[r*64 + jl]
    }
    __syncthreads();

#pragma unroll
    for (int it = 0; it < 5; ++it) {
        int p = it * 512 + t;
        int lane8 = p & 63, bk = p >> 6;
        int colg8 = lane8 & 15, kq = lane8 >> 4;
        int ihq = bk / 10;
        int s = bk - ihq * 10;
        int i = ihq * 16 + colg8;
        int k0 = s * 32 + kq * 8;
        int rr = k0 >> 6, jl0 = k0 & 63;
        uint2 mk8 = *(const uint2*)&maskp[((size_t)(ib + i) << 8) + j0 + jl0];
        float sv = Ss[i * 5 + rr];
        float esum = 0.f;
        bf16x8 pv;
#pragma unroll
        for (int e = 0; e < 8; ++e) {
            unsigned mb = ((e < 4 ? (mk8.x >> (8 * e)) : (mk8.y >> (8 * (e - 4)))) >> rr) & 1u;
            float v = lrelu(sv + Ds2[rr * 64 + jl0 + e]);
            float ev = mb ? __expf(v) : 0.f;
            unsigned short q = f2bf(ev);
            pv[e] = (short)q;
            esum += __uint_as_float((unsigned)q << 16);
        }
        *(bf16x8*)&Ps[p * 8] = pv;
        atomicAdd(&Zrow[i], esum);
    }
    __syncthreads();
    if (t < 64) Zpart[(size_t)js * 8192 + ib + t] = Zrow[t];

    const int w = t >> 6, lane = t & 63;
    const int ihq = w & 3, ch = w >> 2;
    const int colg = lane & 15, rquad = lane >> 4;
    f32x4 acc[4] = {};
    const size_t bbase = (size_t)(b * 5) * 32 * 1024;
#pragma unroll
    for (int s = 0; s < 10; ++s) {
        bf16x8 af = *(const bf16x8*)&Ps[((ihq * 10 + s) * 64 + lane) * 8];
        const int r = s >> 1;
        const int joct = (j0 >> 3) + (s & 1) * 4 + rquad;
        const size_t tbase = bbase + (size_t)(r * 32 + joct) * 1024;
#pragma unroll
        for (int ct = 0; ct < 4; ++ct) {
            int c = ch * 64 + ct * 16 + colg;
            bf16x8 bfv = *(const bf16x8*)&hTf[tbase + (size_t)c * 8];
            acc[ct] = __builtin_amdgcn_mfma_f32_16x16x32_bf16(af, bfv, acc[ct], 0, 0, 0);
        }
    }
    float* op = aggP + (size_t)js * 1048576;   // 8192*128
    const int irow = ib + ihq * 16 + rquad * 4;
#pragma unroll
    for (int ct = 0; ct < 4; ++ct) {
        int c = ch * 64 + ct * 16 + colg;
#pragma unroll
        for (int reg = 0; reg < 4; ++reg)
            op[(size_t)(irow + reg) * 128 + c] = acc[ct][reg];
    }
}

// =======================================================================================
// k_norm: Abf[row][c] = bf16( lrelu( (sum_js aggP) / (sum_js Zpart) ) )
// =======================================================================================
__global__ __launch_bounds__(256) void k_norm(const float* __restrict__ aggP,
                                              const float* __restrict__ Zpart,
                                              unsigned short* __restrict__ Abf) {
    int idx8 = blockIdx.x * 256 + threadIdx.x;
    int row = idx8 >> 4, c0 = (idx8 & 15) * 8;
    float Z = Zpart[row] + Zpart[8192 + row] + Zpart[16384 + row] + Zpart[24576 + row];
    float zi = 1.f / Z;
    size_t o = (size_t)row * 128 + c0;
    float v[8];
#pragma unroll
    for (int h = 0; h < 2; ++h) {
        float4 s0 = *(const float4*)&aggP[o + h * 4];
        float4 s1 = *(const float4*)&aggP[o + h * 4 + 1048576];
        float4 s2 = *(const float4*)&aggP[o + h * 4 + 2097152];
        float4 s3 = *(const float4*)&aggP[o + h * 4 + 3145728];
        v[h * 4 + 0] = s0.x + s1.x + s2.x + s3.x;
        v[h * 4 + 1] = s0.y + s1.y + s2.y + s3.y;
        v[h * 4 + 2] = s0.z + s1.z + s2.z + s3.z;
        v[h * 4 + 3] = s0.w + s1.w + s2.w + s3.w;
    }
    bf16x8 ob;
#pragma unroll
    for (int e = 0; e < 8; ++e) ob[e] = (short)f2bf(lrelu(v[e] * zi));
    *(bf16x8*)&Abf[o] = ob;
}

// =======================================================================================
// k_pool stage 1: per (n-chunk of 32, b): chunk sum & max of h3 = (sum aggP)/Z over n.
// grid (8, 32), 256 threads (c = t&127, sub = t>>7 covers 16 n each). Coalesced over c.
// =======================================================================================
__global__ __launch_bounds__(256) void k_pool(const float* __restrict__ aggP,
                                              const float* __restrict__ Zpart,
                                              float* __restrict__ poolS,
                                              float* __restrict__ poolM) {
    int nc = blockIdx.x, b = blockIdx.y;
    int t = threadIdx.x;
    int c = t & 127, sub = t >> 7;
    __shared__ float Zl[32];
    __shared__ float Sh[2][128], Mh[2][128];
    if (t < 32) {
        int rowg = b * 256 + nc * 32 + t;
        Zl[t] = 1.f / (Zpart[rowg] + Zpart[8192 + rowg] + Zpart[16384 + rowg] + Zpart[24576 + rowg]);
    }
    __syncthreads();
    float sm = 0.f, mx = -3.4e38f;
#pragma unroll
    for (int nn = 0; nn < 16; ++nn) {
        int nl = sub * 16 + nn;
        size_t o = (size_t)(b * 256 + nc * 32 + nl) * 128 + c;
        float v = (aggP[o] + aggP[o + 1048576] + aggP[o + 2097152] + aggP[o + 3145728]) * Zl[nl];
        sm += v; mx = fmaxf(mx, v);
    }
    Sh[sub][c] = sm; Mh[sub][c] = mx;
    __syncthreads();
    if (t < 128) {
        poolS[(b * 8 + nc) * 128 + t] = Sh[0][t] + Sh[1][t];
        poolM[(b * 8 + nc) * 128 + t] = fmaxf(Mh[0][t], Mh[1][t]);
    }
}

// =======================================================================================
// k_mlp1: z1[b][o] = lrelu( z . We1T[o] + be1[o] ), z = [x | mean | max] (1280).
// grid (16 og, 32 b), 256 threads = 4 waves; each wave computes 4 outputs (shfl-reduce).
// =======================================================================================
__global__ __launch_bounds__(256) void k_mlp1(const float* __restrict__ x,
                                              const float* __restrict__ poolS,
                                              const float* __restrict__ poolM,
                                              const float* __restrict__ We1T,
                                              const float* __restrict__ be1,
                                              float* __restrict__ z1g) {
    int og = blockIdx.x, b = blockIdx.y;
    int t = threadIdx.x;
    __shared__ float zs[1280];
    for (int i = t; i < 1024; i += 256) zs[i] = x[b * 1024 + i];
    if (t < 128) {
        float s = 0.f;
#pragma unroll
        for (int nc = 0; nc < 8; ++nc) s += poolS[(b * 8 + nc) * 128 + t];
        zs[1024 + t] = s * (1.f / 256.f);
    } else {
        int f = t - 128;
        float mx = -3.4e38f;
#pragma unroll
        for (int nc = 0; nc < 8; ++nc) mx = fmaxf(mx, poolM[(b * 8 + nc) * 128 + f]);
        zs[1152 + f] = mx;
    }
    __syncthreads();
    int w = t >> 6, lane = t & 63;
#pragma unroll
    for (int oo = 0; oo < 4; ++oo) {
        int o = og * 16 + w * 4 + oo;
        float s = 0.f;
#pragma unroll
        for (int i = 0; i < 20; ++i) {
            int k = i * 64 + lane;
            s += zs[k] * We1T[(size_t)o * 1280 + k];
        }
#pragma unroll
        for (int off = 32; off > 0; off >>= 1) s += __shfl_down(s, off);
        if (lane == 0) z1g[b * 256 + o] = lrelu(s + be1[o]);
    }
}

// ---------------- MLP layers 2+3 ----------------
__global__ __launch_bounds__(256) void k_mlp23(const float* __restrict__ z1g,
                                               const float* __restrict__ We2,
                                               const float* __restrict__ be2,
                                               const float* __restrict__ We3,
                                               const float* __restrict__ be3,
                                               float* __restrict__ out) {
    int b = blockIdx.x, t = threadIdx.x;
    __shared__ float zs[256], z2s[32];
    zs[t] = z1g[b * 256 + t];
    __syncthreads();
    if (t < 32) {
        float s2 = be2[t];
        for (int k = 0; k < 256; ++k) s2 += zs[k] * We2[k * 32 + t];
        z2s[t] = lrelu(s2);
    }
    __syncthreads();
    if (t == 0) {
        float s3 = be3[0];
#pragma unroll
        for (int k = 0; k < 32; ++k) s3 += z2s[k] * We3[k];
        out[b] = s3;
    }
}

// ---------------- workspace layout ----------------
constexpr size_t O_MASK  = 0;                                  // 2 MB
constexpr size_t O_SRCP  = 2097152;                            // 2 x 40960 floats
constexpr size_t O_DSTP  = O_SRCP + 2ull * 40960 * 4;
constexpr size_t O_ZP    = O_DSTP + 2ull * 40960 * 4;          // 4 x 8192 floats
constexpr size_t O_AGG   = O_ZP + 4ull * 8192 * 4;             // 16.8 MB
constexpr size_t O_ABF   = O_AGG + 4ull * 1048576 * 4;         // 2 MB
constexpr size_t O_HT    = O_ABF + 1048576ull * 2;             // 10.5 MB
constexpr size_t O_WT1   = O_HT + 5242880ull * 2;
constexpr size_t O_WT2   = O_WT1 + 640ull * 64 * 2;
constexpr size_t O_WT3   = O_WT2 + 640ull * 128 * 2;
constexpr size_t O_WE1T  = O_WT3 + 640ull * 128 * 2;           // 1.31 MB
constexpr size_t O_POOLS = O_WE1T + 256ull * 1280 * 4;
constexpr size_t O_POOLM = O_POOLS + 32ull * 8 * 128 * 4;
constexpr size_t O_Z1    = O_POOLM + 32ull * 8 * 128 * 4;      // 32 KB

extern "C" void kernel_launch(void* const* d_in, const int* in_sizes, int n_in,
                              void* d_out, int out_size, void* d_ws, size_t ws_size,
                              hipStream_t stream) {
    const float* x       = (const float*)d_in[0];
    const float* y_atoms = (const float*)d_in[1];
    const int*   y_bonds = (const int*)d_in[2];
    const float* W1 = (const float*)d_in[3];
    const float* b1 = (const float*)d_in[4];
    const float* a1 = (const float*)d_in[5];
    const float* W2 = (const float*)d_in[6];
    const float* b2 = (const float*)d_in[7];
    const float* a2 = (const float*)d_in[8];
    const float* W3 = (const float*)d_in[9];
    const float* b3 = (const float*)d_in[10];
    const float* a3 = (const float*)d_in[11];
    const float* We1 = (const float*)d_in[12];
    const float* be1 = (const float*)d_in[13];
    const float* We2 = (const float*)d_in[14];
    const float* be2 = (const float*)d_in[15];
    const float* We3 = (const float*)d_in[16];
    const float* be3 = (const float*)d_in[17];
    float* out = (float*)d_out;

    char* ws = (char*)d_ws;
    unsigned char* maskp = (unsigned char*)(ws + O_MASK);
    float* srcp = (float*)(ws + O_SRCP);
    float* dstp = (float*)(ws + O_DSTP);
    float* Zpart = (float*)(ws + O_ZP);
    float* aggP = (float*)(ws + O_AGG);
    unsigned short* Abf = (unsigned short*)(ws + O_ABF);
    unsigned short* hTf = (unsigned short*)(ws + O_HT);
    unsigned short* WT1 = (unsigned short*)(ws + O_WT1);
    unsigned short* WT2 = (unsigned short*)(ws + O_WT2);
    unsigned short* WT3 = (unsigned short*)(ws + O_WT3);
    float* We1T  = (float*)(ws + O_WE1T);
    float* poolS = (float*)(ws + O_POOLS);
    float* poolM = (float*)(ws + O_POOLM);
    float* z1g   = (float*)(ws + O_Z1);

    dim3 blk(256);

    k_prepw<<<62, blk, 0, stream>>>(W1, W2, W3, We1, WT1, WT2, WT3, We1T);
    k_pack<<<8192, blk, 0, stream>>>(y_bonds, maskp);

    // layer 1
    k_gemm_h<64, false><<<dim3(10, 128), blk, 0, stream>>>(
        y_atoms, nullptr, WT1, b1, a1, srcp, dstp, hTf);
    k_agg<<<dim3(4, 4, 32), dim3(512), 0, stream>>>(hTf, srcp, dstp, maskp, aggP, Zpart);

    // layer 2
    k_norm<<<512, blk, 0, stream>>>(aggP, Zpart, Abf);
    k_gemm_h<128, true><<<dim3(10, 128), blk, 0, stream>>>(
        nullptr, Abf, WT2, b2, a2, srcp, dstp, hTf);
    k_agg<<<dim3(4, 4, 32), dim3(512), 0, stream>>>(hTf, srcp, dstp, maskp, aggP, Zpart);

    // layer 3
    k_norm<<<512, blk, 0, stream>>>(aggP, Zpart, Abf);
    k_gemm_h<128, true><<<dim3(10, 128), blk, 0, stream>>>(
        nullptr, Abf, WT3, b3, a3, srcp, dstp, hTf);
    k_agg<<<dim3(4, 4, 32), dim3(512), 0, stream>>>(hTf, srcp, dstp, maskp, aggP, Zpart);

    // pooling + MLP
    k_pool<<<dim3(8, 32), blk, 0, stream>>>(aggP, Zpart, poolS, poolM);
    k_mlp1<<<dim3(16, 32), blk, 0, stream>>>(x, poolS, poolM, We1T, be1, z1g);
    k_mlp23<<<32, blk, 0, stream>>>(z1g, We2, be2, We3, be3, out);
}

// Round 8
// 228.215 us; speedup vs baseline: 3.0798x; 1.0403x over previous
//
#include <hip/hip_runtime.h>
#include <cstddef>

#define BB 32
#define NN 256
#define RR 5

typedef __attribute__((ext_vector_type(8))) short bf16x8;
typedef __attribute__((ext_vector_type(4))) float f32x4;

__device__ __forceinline__ float lrelu(float x) { return x >= 0.f ? x : 0.2f * x; }
// RNE float -> bf16
__device__ __forceinline__ unsigned short f2bf(float x) {
    unsigned u = __float_as_uint(x);
    u += 0x7FFFu + ((u >> 16) & 1u);
    return (unsigned short)(u >> 16);
}

// =======================================================================================
// k_prep: fused one-time prep.
// blocks 0..29: W (K x 640 fp32) -> WT (640 x K bf16); blocks 30..61: We1 -> We1T;
// blocks 62..8253: pack y_bonds -> maskp (5-bit per (b,i,j)).
// =======================================================================================
__global__ __launch_bounds__(256) void k_prep(const float* __restrict__ W1,
                                              const float* __restrict__ W2,
                                              const float* __restrict__ W3,
                                              const float* __restrict__ We1,
                                              const int* __restrict__ bonds,
                                              unsigned short* __restrict__ WT1,
                                              unsigned short* __restrict__ WT2,
                                              unsigned short* __restrict__ WT3,
                                              float* __restrict__ We1T,
                                              unsigned char* __restrict__ maskp) {
    __shared__ float Ls[40][256];
    int blk = blockIdx.x;
    int t = threadIdx.x;
    if (blk < 30) {
        int layer = blk / 10, nt = blk % 10;
        const float* W;
        unsigned short* WT;
        int K;
        if (layer == 0)      { W = W1; WT = WT1; K = 64; }
        else if (layer == 1) { W = W2; WT = WT2; K = 128; }
        else                 { W = W3; WT = WT3; K = 128; }
        int n = nt * 64 + (t & 63);
        for (int kg = (int)(t >> 6); kg < K / 8; kg += 4) {
            bf16x8 v;
#pragma unroll
            for (int e = 0; e < 8; ++e) v[e] = (short)f2bf(W[(size_t)(kg * 8 + e) * 640 + n]);
            *(bf16x8*)&WT[(size_t)n * K + kg * 8] = v;
        }
    } else if (blk < 62) {
        int bt = blk - 30;                         // k-range [bt*40, bt*40+40)
        for (int kk = 0; kk < 40; ++kk)
            Ls[kk][t] = We1[(size_t)(bt * 40 + kk) * 256 + t];
        __syncthreads();
#pragma unroll
        for (int q = 0; q < 10; ++q) {
            float4 v;
            v.x = Ls[q * 4 + 0][t]; v.y = Ls[q * 4 + 1][t];
            v.z = Ls[q * 4 + 2][t]; v.w = Ls[q * 4 + 3][t];
            *(float4*)&We1T[(size_t)t * 1280 + bt * 40 + q * 4] = v;
        }
    } else {
        int idx = (blk - 62) * 256 + t;
        const int* p = bonds + (size_t)idx * 5;
        unsigned m = 0;
#pragma unroll
        for (int r = 0; r < 5; ++r) m |= (p[r] == 1) ? (1u << r) : 0u;
        maskp[idx] = (unsigned char)m;
    }
}

// =======================================================================================
// gemm_h: h = A(8192 x K) @ W(K x 640) + bias, MFMA bf16 (fp32 accum), no LDS staging.
// Emits src/dst partial dots (2 halves) and hTf fragment-native:
//   hTf[((b*5 + r)*32 + joct)*1024 + c*8 + e]   (joct = j/8, e = j%8)
// grid (10 n-tiles of 64, 128 m-tiles of 64), 256 threads = 4 waves.
// =======================================================================================
template <int K, bool ABF16>
__global__ __launch_bounds__(256) void k_gemm_h(const float* __restrict__ Af32,
                                                const unsigned short* __restrict__ Abf,
                                                const unsigned short* __restrict__ WTg,
                                                const float* __restrict__ bias,
                                                const float* __restrict__ avec,
                                                float* __restrict__ srcp,
                                                float* __restrict__ dstp,
                                                unsigned short* __restrict__ hTf) {
    const int t = threadIdx.x;
    const int n0 = blockIdx.x * 64, m0 = blockIdx.y * 64;
    const int w = t >> 6, lane = t & 63;
    const int colg = lane & 15, rquad = lane >> 4;
    const int m = m0 + w * 16 + colg;        // A row this lane reads
    const int koff = rquad * 8;

    f32x4 acc[4] = {};
#pragma unroll
    for (int kk = 0; kk < K; kk += 32) {
        bf16x8 af;
        if (ABF16) {
            af = *(const bf16x8*)&Abf[(size_t)m * K + kk + koff];
        } else {
            size_t off = (size_t)m * K + kk + koff;
            float4 q0 = *(const float4*)&Af32[off];
            float4 q1 = *(const float4*)&Af32[off + 4];
            af[0] = (short)f2bf(q0.x); af[1] = (short)f2bf(q0.y);
            af[2] = (short)f2bf(q0.z); af[3] = (short)f2bf(q0.w);
            af[4] = (short)f2bf(q1.x); af[5] = (short)f2bf(q1.y);
            af[6] = (short)f2bf(q1.z); af[7] = (short)f2bf(q1.w);
        }
#pragma unroll
        for (int ct = 0; ct < 4; ++ct) {
            bf16x8 bfv = *(const bf16x8*)&WTg[(size_t)(n0 + ct * 16 + colg) * K + kk + koff];
            acc[ct] = __builtin_amdgcn_mfma_f32_16x16x32_bf16(af, bfv, acc[ct], 0, 0, 0);
        }
    }

    // ---- epilogue: bias, src/dst partial dots (shfl-reduce over colg), hTf stores ----
    const int r = n0 >> 7, chalf = n0 & 127;
    const int b = m0 >> 8, jb = m0 & 255;
    float val[4][4];
    float ssum[4] = {0.f, 0.f, 0.f, 0.f}, dsum[4] = {0.f, 0.f, 0.f, 0.f};
#pragma unroll
    for (int ct = 0; ct < 4; ++ct) {
        int cg = chalf + ct * 16 + colg;
        float bv = bias[n0 + ct * 16 + colg];
        float asr = avec[r * 256 + cg];
        float ads = avec[r * 256 + 128 + cg];
#pragma unroll
        for (int reg = 0; reg < 4; ++reg) {
            float v = acc[ct][reg] + bv;
            val[ct][reg] = v;
            ssum[reg] += v * asr;
            dsum[reg] += v * ads;
        }
    }
#pragma unroll
    for (int mk = 1; mk < 16; mk <<= 1)
#pragma unroll
        for (int reg = 0; reg < 4; ++reg) {
            ssum[reg] += __shfl_xor(ssum[reg], mk);
            dsum[reg] += __shfl_xor(dsum[reg], mk);
        }
    if (colg == 0) {
        int half = (n0 >> 6) & 1;
#pragma unroll
        for (int reg = 0; reg < 4; ++reg) {
            int row = m0 + w * 16 + rquad * 4 + reg;
            srcp[half * 40960 + row * 5 + r] = ssum[reg];
            dstp[half * 40960 + row * 5 + r] = dsum[reg];
        }
    }
    // hTf direct stores: reg-quad = 4 consecutive j (8 B contiguous)
    {
        const int joct = (jb >> 3) + w * 2 + (rquad >> 1);
        const size_t tile = (size_t)((b * 5 + r) * 32 + joct) * 1024;
        const int sub = (rquad & 1) * 4;
#pragma unroll
        for (int ct = 0; ct < 4; ++ct) {
            int c = chalf + ct * 16 + colg;
            uint2 pk;
            pk.x = (unsigned)f2bf(val[ct][0]) | ((unsigned)f2bf(val[ct][1]) << 16);
            pk.y = (unsigned)f2bf(val[ct][2]) | ((unsigned)f2bf(val[ct][3]) << 16);
            *(uint2*)&hTf[tile + (size_t)c * 8 + sub] = pk;
        }
    }
}

// =======================================================================================
// k_agg: per block = (16-row i-tile, b), FULL j range (K = 1280). Unnormalized e in LDS,
// Zrow complete in-block -> epilogue normalizes and writes:
//   LAST=false: Abf[row][c] = bf16(lrelu(h/Z))  (next layer's A)
//   LAST=true : pool partials poolS/poolM[(b*16+it)*128+c] (no leaky; h3 = h/Z)
// 256 threads = 4 waves; wave w covers c in [w*32, w*32+32).
// grid (16 i-tiles, 32 b) = 512 blocks. LDS ~54 KB -> 2 blocks/CU.
// =======================================================================================
template <bool LAST>
__global__ __launch_bounds__(256) void k_agg(const unsigned short* __restrict__ hTf,
                                             const float* __restrict__ srcp,
                                             const float* __restrict__ dstp,
                                             const unsigned char* __restrict__ maskp,
                                             unsigned short* __restrict__ Abf,
                                             float* __restrict__ poolS,
                                             float* __restrict__ poolM) {
    __shared__ unsigned short Ps[40 * 64 * 8];   // 40 k-steps x 64 chunks x 8 bf16 = 40 KB
    __shared__ float Ss[80], Ds2[1280], Zrow[16], Zi[16];
    __shared__ float Os[16][132];                // normalized outputs staging
    const int t = threadIdx.x;
    const int itile = blockIdx.x, b = blockIdx.y;
    const int ib = b * 256 + itile * 16;

    if (t < 80) Ss[t] = srcp[(size_t)ib * 5 + t] + srcp[40960 + (size_t)ib * 5 + t];
    if (t >= 80 && t < 96) Zrow[t - 80] = 0.f;
    for (int idx = t; idx < 1280; idx += 256) {
        int jl = idx & 255, rr = idx >> 8;
        size_t o = (size_t)(b * 256 + jl) * 5 + rr;
        Ds2[rr * 256 + jl] = dstp[o] + dstp[40960 + o];   // Ds2[k], k = r*256 + j
    }
    __syncthreads();

    // P generation: 2560 chunks of 8; thread t -> chunks {it*256+t}, i = t&15 fixed
    const int i_mine = t & 15;
    {
        float sv5[5];
#pragma unroll
        for (int r = 0; r < 5; ++r) sv5[r] = Ss[i_mine * 5 + r];
        float esum = 0.f;
#pragma unroll
        for (int it = 0; it < 10; ++it) {
            int p = it * 256 + t;
            int lane8 = p & 63, s = p >> 6;
            int kq = lane8 >> 4;
            int k0 = s * 32 + kq * 8;
            int rr = k0 >> 8, j0 = k0 & 255;
            uint2 mk8 = *(const uint2*)&maskp[((size_t)(ib + i_mine) << 8) + j0];
            float sv = sv5[rr];
            bf16x8 pv;
#pragma unroll
            for (int e = 0; e < 8; ++e) {
                unsigned mb = ((e < 4 ? (mk8.x >> (8 * e)) : (mk8.y >> (8 * (e - 4)))) >> rr) & 1u;
                float v = lrelu(sv + Ds2[k0 + e]);
                float ev = mb ? __expf(v) : 0.f;
                unsigned short q = f2bf(ev);
                pv[e] = (short)q;
                esum += __uint_as_float((unsigned)q << 16);
            }
            *(bf16x8*)&Ps[p * 8] = pv;
        }
        atomicAdd(&Zrow[i_mine], esum);
    }
    __syncthreads();
    if (t < 16) Zi[t] = 1.f / Zrow[t];
    __syncthreads();

    // MFMA: wave w -> c in [w*32, w*32+32); K = 1280 in 40 steps of 32
    const int w = t >> 6, lane = t & 63;
    const int colg = lane & 15, rquad = lane >> 4;
    f32x4 acc[2] = {};
    const size_t bbase = (size_t)(b * 5) * 32 * 1024;
#pragma unroll
    for (int s = 0; s < 40; ++s) {
        bf16x8 af = *(const bf16x8*)&Ps[(s * 64 + lane) * 8];
        const size_t tbase = bbase + (size_t)((s >> 3) * 32 + (s & 7) * 4 + rquad) * 1024;
#pragma unroll
        for (int ct = 0; ct < 2; ++ct) {
            int c = w * 32 + ct * 16 + colg;
            bf16x8 bfv = *(const bf16x8*)&hTf[tbase + (size_t)c * 8];
            acc[ct] = __builtin_amdgcn_mfma_f32_16x16x32_bf16(af, bfv, acc[ct], 0, 0, 0);
        }
    }
    __syncthreads();   // Ps dead; stage normalized outputs
#pragma unroll
    for (int ct = 0; ct < 2; ++ct) {
        int c = w * 32 + ct * 16 + colg;
#pragma unroll
        for (int reg = 0; reg < 4; ++reg) {
            int i = rquad * 4 + reg;
            Os[i][c] = acc[ct][reg] * Zi[i];
        }
    }
    __syncthreads();

    if (!LAST) {
        int i = t >> 4, c0 = (t & 15) * 8;
        bf16x8 ob;
#pragma unroll
        for (int e = 0; e < 8; ++e) ob[e] = (short)f2bf(lrelu(Os[i][c0 + e]));
        *(bf16x8*)&Abf[(size_t)(ib + i) * 128 + c0] = ob;
    } else {
        if (t < 128) {
            float sm = 0.f, mx = -3.4e38f;
#pragma unroll
            for (int i = 0; i < 16; ++i) {
                float v = Os[i][t];
                sm += v; mx = fmaxf(mx, v);
            }
            poolS[(b * 16 + itile) * 128 + t] = sm;
            poolM[(b * 16 + itile) * 128 + t] = mx;
        }
    }
}

// =======================================================================================
// k_mlp1: z1[b][o] = lrelu( z . We1T[o] + be1[o] ), z = [x | mean | max] (1280).
// grid (16 og, 32 b), 256 threads = 4 waves; each wave computes 4 outputs (shfl-reduce).
// =======================================================================================
__global__ __launch_bounds__(256) void k_mlp1(const float* __restrict__ x,
                                              const float* __restrict__ poolS,
                                              const float* __restrict__ poolM,
                                              const float* __restrict__ We1T,
                                              const float* __restrict__ be1,
                                              float* __restrict__ z1g) {
    int og = blockIdx.x, b = blockIdx.y;
    int t = threadIdx.x;
    __shared__ float zs[1280];
    for (int i = t; i < 1024; i += 256) zs[i] = x[b * 1024 + i];
    if (t < 128) {
        float s = 0.f;
#pragma unroll
        for (int nc = 0; nc < 16; ++nc) s += poolS[(b * 16 + nc) * 128 + t];
        zs[1024 + t] = s * (1.f / 256.f);
    } else {
        int f = t - 128;
        float mx = -3.4e38f;
#pragma unroll
        for (int nc = 0; nc < 16; ++nc) mx = fmaxf(mx, poolM[(b * 16 + nc) * 128 + f]);
        zs[1152 + f] = mx;
    }
    __syncthreads();
    int w = t >> 6, lane = t & 63;
#pragma unroll
    for (int oo = 0; oo < 4; ++oo) {
        int o = og * 16 + w * 4 + oo;
        float s = 0.f;
#pragma unroll
        for (int i = 0; i < 20; ++i) {
            int k = i * 64 + lane;
            s += zs[k] * We1T[(size_t)o * 1280 + k];
        }
#pragma unroll
        for (int off = 32; off > 0; off >>= 1) s += __shfl_down(s, off);
        if (lane == 0) z1g[b * 256 + o] = lrelu(s + be1[o]);
    }
}

// ---------------- MLP layers 2+3 ----------------
__global__ __launch_bounds__(256) void k_mlp23(const float* __restrict__ z1g,
                                               const float* __restrict__ We2,
                                               const float* __restrict__ be2,
                                               const float* __restrict__ We3,
                                               const float* __restrict__ be3,
                                               float* __restrict__ out) {
    int b = blockIdx.x, t = threadIdx.x;
    __shared__ float zs[256], z2s[32];
    zs[t] = z1g[b * 256 + t];
    __syncthreads();
    if (t < 32) {
        float s2 = be2[t];
        for (int k = 0; k < 256; ++k) s2 += zs[k] * We2[k * 32 + t];
        z2s[t] = lrelu(s2);
    }
    __syncthreads();
    if (t == 0) {
        float s3 = be3[0];
#pragma unroll
        for (int k = 0; k < 32; ++k) s3 += z2s[k] * We3[k];
        out[b] = s3;
    }
}

// ---------------- workspace layout ----------------
constexpr size_t O_MASK  = 0;                                  // 2 MB
constexpr size_t O_SRCP  = 2097152;                            // 2 x 40960 floats
constexpr size_t O_DSTP  = O_SRCP + 2ull * 40960 * 4;
constexpr size_t O_ABF   = O_DSTP + 2ull * 40960 * 4;          // 2 MB bf16
constexpr size_t O_HT    = O_ABF + 1048576ull * 2;             // 10.5 MB
constexpr size_t O_WT1   = O_HT + 5242880ull * 2;
constexpr size_t O_WT2   = O_WT1 + 640ull * 64 * 2;
constexpr size_t O_WT3   = O_WT2 + 640ull * 128 * 2;
constexpr size_t O_WE1T  = O_WT3 + 640ull * 128 * 2;           // 1.31 MB
constexpr size_t O_POOLS = O_WE1T + 256ull * 1280 * 4;         // 32*16*128 fp32
constexpr size_t O_POOLM = O_POOLS + 32ull * 16 * 128 * 4;
constexpr size_t O_Z1    = O_POOLM + 32ull * 16 * 128 * 4;     // 32 KB

extern "C" void kernel_launch(void* const* d_in, const int* in_sizes, int n_in,
                              void* d_out, int out_size, void* d_ws, size_t ws_size,
                              hipStream_t stream) {
    const float* x       = (const float*)d_in[0];
    const float* y_atoms = (const float*)d_in[1];
    const int*   y_bonds = (const int*)d_in[2];
    const float* W1 = (const float*)d_in[3];
    const float* b1 = (const float*)d_in[4];
    const float* a1 = (const float*)d_in[5];
    const float* W2 = (const float*)d_in[6];
    const float* b2 = (const float*)d_in[7];
    const float* a2 = (const float*)d_in[8];
    const float* W3 = (const float*)d_in[9];
    const float* b3 = (const float*)d_in[10];
    const float* a3 = (const float*)d_in[11];
    const float* We1 = (const float*)d_in[12];
    const float* be1 = (const float*)d_in[13];
    const float* We2 = (const float*)d_in[14];
    const float* be2 = (const float*)d_in[15];
    const float* We3 = (const float*)d_in[16];
    const float* be3 = (const float*)d_in[17];
    float* out = (float*)d_out;

    char* ws = (char*)d_ws;
    unsigned char* maskp = (unsigned char*)(ws + O_MASK);
    float* srcp = (float*)(ws + O_SRCP);
    float* dstp = (float*)(ws + O_DSTP);
    unsigned short* Abf = (unsigned short*)(ws + O_ABF);
    unsigned short* hTf = (unsigned short*)(ws + O_HT);
    unsigned short* WT1 = (unsigned short*)(ws + O_WT1);
    unsigned short* WT2 = (unsigned short*)(ws + O_WT2);
    unsigned short* WT3 = (unsigned short*)(ws + O_WT3);
    float* We1T  = (float*)(ws + O_WE1T);
    float* poolS = (float*)(ws + O_POOLS);
    float* poolM = (float*)(ws + O_POOLM);
    float* z1g   = (float*)(ws + O_Z1);

    dim3 blk(256);

    k_prep<<<8254, blk, 0, stream>>>(W1, W2, W3, We1, y_bonds, WT1, WT2, WT3, We1T, maskp);

    // layer 1
    k_gemm_h<64, false><<<dim3(10, 128), blk, 0, stream>>>(
        y_atoms, nullptr, WT1, b1, a1, srcp, dstp, hTf);
    k_agg<false><<<dim3(16, 32), blk, 0, stream>>>(hTf, srcp, dstp, maskp, Abf, nullptr, nullptr);

    // layer 2
    k_gemm_h<128, true><<<dim3(10, 128), blk, 0, stream>>>(
        nullptr, Abf, WT2, b2, a2, srcp, dstp, hTf);
    k_agg<false><<<dim3(16, 32), blk, 0, stream>>>(hTf, srcp, dstp, maskp, Abf, nullptr, nullptr);

    // layer 3
    k_gemm_h<128, true><<<dim3(10, 128), blk, 0, stream>>>(
        nullptr, Abf, WT3, b3, a3, srcp, dstp, hTf);
    k_agg<true><<<dim3(16, 32), blk, 0, stream>>>(hTf, srcp, dstp, maskp, nullptr, poolS, poolM);

    // MLP
    k_mlp1<<<dim3(16, 32), blk, 0, stream>>>(x, poolS, poolM, We1T, be1, z1g);
    k_mlp23<<<32, blk, 0, stream>>>(z1g, We2, be2, We3, be3, out);
}